// Round 7
// baseline (865.745 us; speedup 1.0000x reference)
//
#include <hip/hip_runtime.h>
#include <hip/hip_bf16.h>

// Problem constants (from reference)
#define SN 50000
#define EN 20000
#define KN 128
#define DN 64
#define BN 4096
#define NE 1000000
#define NLAYER 3

// Column-chunk bucketing: chunk = 4096 gather-table rows = 1MB bf16 (L2-resident)
#define CH_SHIFT 12
#define NCH0 5                        // side0 (ui): cols index kdiff, EN -> 5 chunks
#define NCH1 13                       // side1 (iu): cols index stat,  SN -> 13 chunks
#define SIDE1_BASE (SN * NCH0)        // 250000
#define NTOT (SN * NCH0 + EN * NCH1)  // 510000 fine buckets

// Two-pass partition sort
#define BIN_SHIFT 11
#define NBIN ((NTOT + 2047) >> 11)    // 250 coarse bins (2048 fine buckets each)
#define T1 4096                       // edges per part1 tile
#define PG1 ((NE + T1 - 1) / T1)      // 245 tiles per adjacency
#define HB 256                        // hist blocks per adjacency

typedef float f32x4 __attribute__((ext_vector_type(4)));
typedef short bf16x8 __attribute__((ext_vector_type(8)));

__device__ __forceinline__ float sigmoidf_(float v) { return 1.f / (1.f + __expf(-v)); }
__device__ __forceinline__ float bf_lo(unsigned u) { return __uint_as_float(u << 16); }
__device__ __forceinline__ float bf_hi(unsigned u) { return __uint_as_float(u & 0xffff0000u); }
__device__ __forceinline__ float bf_one(unsigned short s) { return __uint_as_float((unsigned)s << 16); }
__device__ __forceinline__ unsigned packbf2(float a, float b) {
    __hip_bfloat16 ha = __float2bfloat16(a), hb = __float2bfloat16(b);
    unsigned short ua = *(unsigned short*)&ha, ub = *(unsigned short*)&hb;
    return (unsigned)ua | ((unsigned)ub << 16);
}
__device__ __forceinline__ unsigned short packbf1(float a) {
    __hip_bfloat16 ha = __float2bfloat16(a);
    return *(unsigned short*)&ha;
}

struct CsrB {
    const int* rows[4]; const int* cols[4]; const float* vals[4];
};

// ---------------------------------------------------------------------------
// Coarse histogram (250 bins), LDS-staged
// ---------------------------------------------------------------------------
__global__ __launch_bounds__(256) void hist_coarse(CsrB c, int* __restrict__ cnt) {
    __shared__ int h[256];
    const int t = threadIdx.x;
    h[t] = 0;
    __syncthreads();
    const int a = blockIdx.x >> 8;
    const int tile = blockIdx.x & 255;
    const int per = (NE + HB - 1) / HB;
    const int beg = tile * per, end = min(beg + per, NE);
    const int side = a >> 1;
    const int nch = side ? NCH1 : NCH0;
    const int basebk = side ? SIDE1_BASE : 0;
    for (int i = beg + t; i < end; i += 256) {
        int B = basebk + c.rows[a][i] * nch + (c.cols[a][i] >> CH_SHIFT);
        atomicAdd(&h[B >> BIN_SHIFT], 1);
    }
    __syncthreads();
    if (h[t]) atomicAdd(&cnt[t], h[t]);
}

// 1-block exclusive scan of 256 coarse counts -> base[257] and tails[256]
__global__ __launch_bounds__(256) void scan_coarse(const int* __restrict__ cnt,
                                                   int* __restrict__ base,
                                                   int* __restrict__ tails) {
    __shared__ int sh[256];
    const int t = threadIdx.x;
    const int v = cnt[t];
    sh[t] = v;
    __syncthreads();
    for (int o = 1; o < 256; o <<= 1) {
        int x = sh[t]; int u = (t >= o) ? sh[t - o] : 0;
        __syncthreads(); sh[t] = x + u; __syncthreads();
    }
    const int ex = sh[t] - v;
    base[t] = ex;
    tails[t] = ex;
    if (t == 255) base[256] = sh[255];
}

// ---------------------------------------------------------------------------
// part1: multisplit edges into coarse-bin segments with coalesced writes.
// Record int2: .x = col(0..15) | fine_bucket_low11(17..27)
//              .y = f32 val, SIGN-ENCODED: negative <=> neg-adjacency (tag 0)
// ---------------------------------------------------------------------------
__global__ __launch_bounds__(512) void part1(CsrB c, int* __restrict__ tails,
                                             int2* __restrict__ stg) {
    __shared__ int2 srec[T1];
    __shared__ unsigned char sbin[T1];
    __shared__ int h[256], offs[256], gbase[256], sc[512];
    const int t = threadIdx.x;
    const int a = blockIdx.x / PG1;
    const int tile = blockIdx.x - a * PG1;
    const int beg = tile * T1;
    const int cnt = min(T1, NE - beg);
    if (t < 256) h[t] = 0;
    __syncthreads();

    int2 rec[8]; int rbin[8]; int rrank[8];
    const int side = a >> 1;
    const int nch = side ? NCH1 : NCH0;
    const int basebk = side ? SIDE1_BASE : 0;
    const float sgn = (a & 1) ? -1.f : 1.f;  // a=0,2: pos(tag1); a=1,3: neg(tag0)
#pragma unroll
    for (int k = 0; k < 8; ++k) {
        int o = t + k * 512;
        if (o < cnt) {
            int i = beg + o;
            int cc = c.cols[a][i];
            int B = basebk + c.rows[a][i] * nch + (cc >> CH_SHIFT);
            int bin = B >> BIN_SHIFT;
            rec[k] = make_int2(cc | ((B & 2047) << 17),
                               __float_as_int(sgn * c.vals[a][i]));
            rbin[k] = bin;
            rrank[k] = atomicAdd(&h[bin], 1);
        } else {
            rbin[k] = -1;
        }
    }
    __syncthreads();
    sc[t] = (t < 256) ? h[t] : 0;
    __syncthreads();
    for (int o = 1; o < 256; o <<= 1) {
        int x = sc[t]; int u = (t >= o) ? sc[t - o] : 0;
        __syncthreads(); sc[t] = x + u; __syncthreads();
    }
    if (t < 256) {
        offs[t] = sc[t] - h[t];
        if (h[t] > 0) gbase[t] = atomicAdd(&tails[t], h[t]);
    }
    __syncthreads();
#pragma unroll
    for (int k = 0; k < 8; ++k) {
        if (rbin[k] >= 0) {
            int pos = offs[rbin[k]] + rrank[k];
            srec[pos] = rec[k];
            sbin[pos] = (unsigned char)rbin[k];
        }
    }
    __syncthreads();
    for (int idx = t; idx < cnt; idx += 512) {
        int b = sbin[idx];
        stg[gbase[b] + (idx - offs[b])] = srec[idx];
    }
}

// ---------------------------------------------------------------------------
// part2: one block per coarse bin. Builds fine histogram+prefix in LDS
// (producing rp_all), then scatters into the bin's own ~128KB window.
// cv record: .x = bare column, .y = sign-encoded f32 value
// ---------------------------------------------------------------------------
__global__ __launch_bounds__(512) void part2(const int* __restrict__ coarseBase,
                                             const int2* __restrict__ stg,
                                             int* __restrict__ rp,
                                             int2* __restrict__ cv) {
    __shared__ int cnt2[2048];
    __shared__ int tsum[512];
    const int b = blockIdx.x;
    const int t = threadIdx.x;
    const int fineBase = b << BIN_SHIFT;
    const int nf = min(2048, NTOT - fineBase);
    const int segBeg = coarseBase[b];
    const int segEnd = coarseBase[b + 1];
    for (int i = t; i < 2048; i += 512) cnt2[i] = 0;
    __syncthreads();
    for (int e = segBeg + t; e < segEnd; e += 512)
        atomicAdd(&cnt2[((unsigned)stg[e].x) >> 17], 1);
    __syncthreads();
    const int i4 = t * 4;
    int v0 = cnt2[i4], v1 = cnt2[i4 + 1], v2 = cnt2[i4 + 2], v3 = cnt2[i4 + 3];
    tsum[t] = v0 + v1 + v2 + v3;
    __syncthreads();
    for (int o = 1; o < 512; o <<= 1) {
        int x = tsum[t]; int u = (t >= o) ? tsum[t - o] : 0;
        __syncthreads(); tsum[t] = x + u; __syncthreads();
    }
    const int pre = (t == 0) ? 0 : tsum[t - 1];
    const int p0 = pre, p1 = pre + v0, p2 = p1 + v1, p3 = p2 + v2;
    cnt2[i4] = p0; cnt2[i4 + 1] = p1; cnt2[i4 + 2] = p2; cnt2[i4 + 3] = p3;
    if (i4 + 0 < nf) rp[fineBase + i4 + 0] = segBeg + p0;
    if (i4 + 1 < nf) rp[fineBase + i4 + 1] = segBeg + p1;
    if (i4 + 2 < nf) rp[fineBase + i4 + 2] = segBeg + p2;
    if (i4 + 3 < nf) rp[fineBase + i4 + 3] = segBeg + p3;
    if (b == NBIN - 1 && t == 511) rp[NTOT] = segEnd;
    __syncthreads();
    for (int e = segBeg + t; e < segEnd; e += 512) {
        int2 r = stg[e];
        int pos = segBeg + atomicAdd(&cnt2[((unsigned)r.x) >> 17], 1);
        cv[pos] = make_int2(r.x & 0xFFFF, r.y);
    }
}

// ---------------------------------------------------------------------------
// fp32 -> bf16 conversion (small weight tables only)
// ---------------------------------------------------------------------------
__global__ __launch_bounds__(256) void f2bf(const float* __restrict__ src,
                                            unsigned short* __restrict__ dst, int n2) {
    int i = blockIdx.x * 256 + threadIdx.x;
    if (i < n2) {
        float2 f = ((const float2*)src)[i];
        ((unsigned*)dst)[i] = packbf2(f.x, f.y);
    }
}

// ---------------------------------------------------------------------------
// Projection MFMA GEMM: out[M,128](bf16) = X[M,KK](f32) @ W[128,KK]^T(bf16)
// ---------------------------------------------------------------------------
template <int KK>
__global__ __launch_bounds__(256) void gemm_proj(const float* __restrict__ X,
                                                 const unsigned short* __restrict__ W,
                                                 unsigned short* __restrict__ out, int M) {
    constexpr int PITCH = KK + 8;
    __shared__ unsigned short Wl[128 * PITCH];
    const int t = threadIdx.x;
    for (int idx = t * 8; idx < 128 * KK; idx += 2048) {
        int r = idx / KK, k = idx - r * KK;
        *(uint4*)(&Wl[r * PITCH + k]) = *(const uint4*)(&W[idx]);
    }
    __syncthreads();
    const int lane = t & 63;
    const int nm = lane & 15;
    const int quad = lane >> 4;
    const int row0 = blockIdx.x * 64 + (t >> 6) * 16;
    if (row0 >= M) return;

    f32x4 acc[8];
#pragma unroll
    for (int nt = 0; nt < 8; ++nt) acc[nt] = (f32x4){0.f, 0.f, 0.f, 0.f};

    const float* xrow = X + (size_t)(row0 + nm) * KK + quad * 8;
#pragma unroll
    for (int ks = 0; ks < KK / 32; ++ks) {
        float4 f0 = *(const float4*)(xrow + ks * 32);
        float4 f1 = *(const float4*)(xrow + ks * 32 + 4);
        unsigned q[4] = {packbf2(f0.x, f0.y), packbf2(f0.z, f0.w),
                         packbf2(f1.x, f1.y), packbf2(f1.z, f1.w)};
        bf16x8 a = *(bf16x8*)q;
#pragma unroll
        for (int nt = 0; nt < 8; ++nt) {
            bf16x8 b = *(const bf16x8*)(&Wl[(nt * 16 + nm) * PITCH + ks * 32 + quad * 8]);
            acc[nt] = __builtin_amdgcn_mfma_f32_16x16x32_bf16(a, b, acc[nt], 0, 0, 0);
        }
    }
    unsigned short* orow = out + (size_t)(row0 + quad * 4) * 128 + nm;
#pragma unroll
    for (int r = 0; r < 4; ++r)
#pragma unroll
        for (int nt = 0; nt < 8; ++nt)
            orow[(size_t)r * 128 + nt * 16] = packbf1(acc[nt][r]);
}

// ---------------------------------------------------------------------------
// Fused dual-weight MFMA GEMM (one GCN layer side, in-place safe):
//   out = (agg1 + d1.*y)@W1^T + (agg0 + d0.*y)@W0^T + (b1+b0)
// ---------------------------------------------------------------------------
__global__ __launch_bounds__(256) void gemm2_mfma(
    const unsigned short* __restrict__ agg1, const unsigned short* __restrict__ agg0,
    const unsigned short* __restrict__ y,
    const float* __restrict__ d1, const float* __restrict__ d0,
    const unsigned short* __restrict__ W1, const unsigned short* __restrict__ W0,
    const float* __restrict__ b1, const float* __restrict__ b0,
    unsigned short* __restrict__ out, int M) {
    constexpr int PITCH = 136;
    __shared__ unsigned short Wl[2 * 128 * PITCH];
    const int t = threadIdx.x;
    for (int idx = t * 8; idx < 128 * 128; idx += 2048) {
        int r = idx >> 7, k = idx & 127;
        *(uint4*)(&Wl[r * PITCH + k]) = *(const uint4*)(&W1[idx]);
        *(uint4*)(&Wl[128 * PITCH + r * PITCH + k]) = *(const uint4*)(&W0[idx]);
    }
    __syncthreads();
    const int lane = t & 63;
    const int nm = lane & 15;
    const int quad = lane >> 4;
    const int row0 = blockIdx.x * 64 + (t >> 6) * 16;
    if (row0 >= M) return;

    const float d1v = d1[row0 + nm];
    const float d0v = d0[row0 + nm];

    f32x4 acc[8];
#pragma unroll
    for (int nt = 0; nt < 8; ++nt) acc[nt] = (f32x4){0.f, 0.f, 0.f, 0.f};

    const size_t rbase = (size_t)(row0 + nm) * 128 + quad * 8;
#pragma unroll
    for (int ks = 0; ks < 4; ++ks) {
        uint4 ua1 = *(const uint4*)(agg1 + rbase + ks * 32);
        uint4 ua0 = *(const uint4*)(agg0 + rbase + ks * 32);
        uint4 uy  = *(const uint4*)(y    + rbase + ks * 32);
        uint4 p1, p0;
        {
            unsigned* a1 = (unsigned*)&ua1; unsigned* a0 = (unsigned*)&ua0;
            unsigned* yy = (unsigned*)&uy;
            unsigned* q1 = (unsigned*)&p1; unsigned* q0 = (unsigned*)&p0;
#pragma unroll
            for (int w = 0; w < 4; ++w) {
                float ylo = bf_lo(yy[w]), yhi = bf_hi(yy[w]);
                q1[w] = packbf2(bf_lo(a1[w]) + d1v * ylo, bf_hi(a1[w]) + d1v * yhi);
                q0[w] = packbf2(bf_lo(a0[w]) + d0v * ylo, bf_hi(a0[w]) + d0v * yhi);
            }
        }
        bf16x8 af1 = *(bf16x8*)&p1;
        bf16x8 af0 = *(bf16x8*)&p0;
#pragma unroll
        for (int nt = 0; nt < 8; ++nt) {
            bf16x8 bw1 = *(const bf16x8*)(&Wl[(nt * 16 + nm) * PITCH + ks * 32 + quad * 8]);
            acc[nt] = __builtin_amdgcn_mfma_f32_16x16x32_bf16(af1, bw1, acc[nt], 0, 0, 0);
            bf16x8 bw0 = *(const bf16x8*)(&Wl[128 * PITCH + (nt * 16 + nm) * PITCH + ks * 32 + quad * 8]);
            acc[nt] = __builtin_amdgcn_mfma_f32_16x16x32_bf16(af0, bw0, acc[nt], 0, 0, 0);
        }
    }
    unsigned short* orow = out + (size_t)(row0 + quad * 4) * 128 + nm;
#pragma unroll
    for (int nt = 0; nt < 8; ++nt) {
        float bb = b1[nt * 16 + nm] + b0[nt * 16 + nm];
#pragma unroll
        for (int r = 0; r < 4; ++r)
            orow[(size_t)r * 128 + nt * 16] = packbf1(acc[nt][r] + bb);
    }
}

// ---------------------------------------------------------------------------
// Merged dual SPMM, both sides in one launch. Sign-encoded tag:
//   all += |v|*g ; pos += max(v,0)*g ; neg = all - pos.
// Wave per row; lane owns cols 2l,2l+1. Unroll 8 for gather MLP.
// Edge records loaded as raw 64-bit ints (low32=col, high32=val bits).
// ---------------------------------------------------------------------------
__global__ __launch_bounds__(256) void spmm_all(
    const int* __restrict__ rp, const long long* __restrict__ cv,
    const unsigned short* __restrict__ gk, const unsigned short* __restrict__ gs,
    unsigned short* __restrict__ as1, unsigned short* __restrict__ as0,
    unsigned short* __restrict__ ae1, unsigned short* __restrict__ ae0) {
    const int wave = (blockIdx.x * 256 + threadIdx.x) >> 6;
    const int lane = threadIdx.x & 63;
    if (wave >= SN + EN) return;
    const bool sideE = wave >= SN;
    const int r = sideE ? wave - SN : wave;
    const int nch = sideE ? NCH1 : NCH0;
    const int* rpb = sideE ? (rp + SIDE1_BASE) : rp;
    const int col2 = lane * 2;
    const unsigned short* gp = (sideE ? gs : gk) + col2;
    unsigned short* o1 = sideE ? ae1 : as1;
    unsigned short* o0 = sideE ? ae0 : as0;

    float aAlo = 0.f, aAhi = 0.f, aPlo = 0.f, aPhi = 0.f;
    int e = rpb[r * nch];
    const int ee = rpb[(r + 1) * nch];

#define BODY(E, U)                                                   \
    {                                                                \
        float sv = __int_as_float((int)((E) >> 32));                 \
        float v = fabsf(sv);                                         \
        float v1 = fmaxf(sv, 0.f);                                   \
        float glo = bf_lo(U), ghi = bf_hi(U);                        \
        aAlo += v * glo; aAhi += v * ghi;                            \
        aPlo += v1 * glo; aPhi += v1 * ghi;                          \
    }
    for (; e + 8 <= ee; e += 8) {
        long long E0 = __builtin_nontemporal_load(&cv[e]);
        long long E1 = __builtin_nontemporal_load(&cv[e + 1]);
        long long E2 = __builtin_nontemporal_load(&cv[e + 2]);
        long long E3 = __builtin_nontemporal_load(&cv[e + 3]);
        long long E4 = __builtin_nontemporal_load(&cv[e + 4]);
        long long E5 = __builtin_nontemporal_load(&cv[e + 5]);
        long long E6 = __builtin_nontemporal_load(&cv[e + 6]);
        long long E7 = __builtin_nontemporal_load(&cv[e + 7]);
        unsigned u0 = *(const unsigned*)(gp + (((int)E0 & 0xFFFF) << 7));
        unsigned u1 = *(const unsigned*)(gp + (((int)E1 & 0xFFFF) << 7));
        unsigned u2 = *(const unsigned*)(gp + (((int)E2 & 0xFFFF) << 7));
        unsigned u3 = *(const unsigned*)(gp + (((int)E3 & 0xFFFF) << 7));
        unsigned u4 = *(const unsigned*)(gp + (((int)E4 & 0xFFFF) << 7));
        unsigned u5 = *(const unsigned*)(gp + (((int)E5 & 0xFFFF) << 7));
        unsigned u6 = *(const unsigned*)(gp + (((int)E6 & 0xFFFF) << 7));
        unsigned u7 = *(const unsigned*)(gp + (((int)E7 & 0xFFFF) << 7));
        BODY(E0, u0) BODY(E1, u1) BODY(E2, u2) BODY(E3, u3)
        BODY(E4, u4) BODY(E5, u5) BODY(E6, u6) BODY(E7, u7)
    }
    for (; e < ee; ++e) {
        long long E0 = __builtin_nontemporal_load(&cv[e]);
        unsigned u0 = *(const unsigned*)(gp + (((int)E0 & 0xFFFF) << 7));
        BODY(E0, u0)
    }
#undef BODY
    const int base = (r << 7) + col2;
    *(unsigned*)&o1[base] = packbf2(aPlo, aPhi);
    *(unsigned*)&o0[base] = packbf2(aAlo - aPlo, aAhi - aPhi);
}

// ---------------------------------------------------------------------------
// fp32 tiled GEMM for the head: out = act( X @ |W|^T + b )
// ---------------------------------------------------------------------------
template <int KK, int NCOLS, int ROWS, bool ABSW, bool SIG>
__global__ __launch_bounds__(256) void gemm_xwT(const float* __restrict__ X,
                                                const float* __restrict__ W,
                                                const float* __restrict__ bias,
                                                float* __restrict__ out, int M) {
    constexpr int KP = 32;
    constexpr int NG = 256 / NCOLS;
    constexpr int RT = ROWS / NG;
    __shared__ float BT[KP * (NCOLS + 1)];
    __shared__ float Xl[ROWS * (KK + 1)];
    const int t = threadIdx.x;
    const int j = t % NCOLS;
    const int rg = t / NCOLS;
    const int row0 = blockIdx.x * ROWS;

    for (int idx = t; idx < ROWS * KK; idx += 256) {
        int r = idx / KK, k = idx % KK;
        int gr = row0 + r;
        Xl[r * (KK + 1) + k] = (gr < M) ? X[gr * KK + k] : 0.f;
    }
    float acc[RT];
#pragma unroll
    for (int i = 0; i < RT; ++i) acc[i] = 0.f;

    for (int k0 = 0; k0 < KK; k0 += KP) {
        __syncthreads();
        for (int idx = t; idx < NCOLS * KP; idx += 256) {
            int jj = idx / KP, kp = idx % KP;
            float w = W[jj * KK + k0 + kp];
            BT[kp * (NCOLS + 1) + jj] = ABSW ? fabsf(w) : w;
        }
        __syncthreads();
#pragma unroll
        for (int kp = 0; kp < KP; ++kp) {
            float b = BT[kp * (NCOLS + 1) + j];
#pragma unroll
            for (int rr = 0; rr < RT; ++rr)
                acc[rr] += Xl[(rg * RT + rr) * (KK + 1) + k0 + kp] * b;
        }
    }
    float bj = bias ? bias[j] : 0.f;
#pragma unroll
    for (int rr = 0; rr < RT; ++rr) {
        int gr = row0 + rg * RT + rr;
        if (gr < M) {
            float v = acc[rr] + bj;
            out[gr * NCOLS + j] = SIG ? sigmoidf_(v) : v;
        }
    }
}

// ---------------------------------------------------------------------------
// Head kernels
// ---------------------------------------------------------------------------
__global__ __launch_bounds__(128) void head1_kernel(
    const int* __restrict__ stu_id, const int* __restrict__ exer_id,
    const float* __restrict__ kn_emb, const unsigned short* __restrict__ stat,
    const unsigned short* __restrict__ kdiff, const float* __restrict__ stu_bias,
    const float* __restrict__ e_disc, float* __restrict__ x) {
    const int b = blockIdx.x;
    const int k = threadIdx.x;
    const int sid = stu_id[b], eid = exer_id[b];
    float disc = sigmoidf_(e_disc[eid]);
    float sb = sigmoidf_(bf_one(stat[(sid << 7) + k]) + stu_bias[sid]);
    float kd = sigmoidf_(bf_one(kdiff[(eid << 7) + k]));
    x[(b << 7) + k] = disc * (sb - kd) * kn_emb[(b << 7) + k];
}

__global__ __launch_bounds__(256) void pn3_kernel(const float* __restrict__ h2,
                                                  const float* __restrict__ w3,
                                                  const float* __restrict__ b3,
                                                  float* __restrict__ out) {
    __shared__ float wl[128];
    const int t = threadIdx.x;
    if (t < 128) wl[t] = fabsf(w3[t]);
    __syncthreads();
    const int b = blockIdx.x * 256 + t;
    float acc = 0.f;
#pragma unroll 4
    for (int k = 0; k < 128; ++k) acc += h2[(b << 7) + k] * wl[k];
    out[b] = sigmoidf_(acc + b3[0]);
}

// ---------------------------------------------------------------------------
// Launch
// ---------------------------------------------------------------------------
static inline size_t align256(size_t x) { return (x + 255) & ~size_t(255); }

extern "C" void kernel_launch(void* const* d_in, const int* in_sizes, int n_in,
                              void* d_out, int out_size, void* d_ws, size_t ws_size,
                              hipStream_t stream) {
    const int*   stu_id   = (const int*)d_in[0];
    const int*   exer_id  = (const int*)d_in[1];
    const float* kn_emb   = (const float*)d_in[2];
    const float* stu_emb  = (const float*)d_in[3];
    const float* exer_emb = (const float*)d_in[4];
    const float* kn_base  = (const float*)d_in[5];
    const float* stu_bias = (const float*)d_in[6];
    const float* e_disc   = (const float*)d_in[7];
    const float* W1_w     = (const float*)d_in[8];
    const float* W1_b     = (const float*)d_in[9];
    const float* W0_w     = (const float*)d_in[10];
    const float* W0_b     = (const float*)d_in[11];
    const float* pn1_w    = (const float*)d_in[12];
    const float* pn1_b    = (const float*)d_in[13];
    const float* pn2_w    = (const float*)d_in[14];
    const float* pn2_b    = (const float*)d_in[15];
    const float* pn3_w    = (const float*)d_in[16];
    const float* pn3_b    = (const float*)d_in[17];
    const int*   ui1_r = (const int*)d_in[18]; const int* ui1_c = (const int*)d_in[19];
    const float* ui1_v = (const float*)d_in[20];
    const int*   iu1_r = (const int*)d_in[21]; const int* iu1_c = (const int*)d_in[22];
    const float* iu1_v = (const float*)d_in[23];
    const int*   ui0_r = (const int*)d_in[24]; const int* ui0_c = (const int*)d_in[25];
    const float* ui0_v = (const float*)d_in[26];
    const int*   iu0_r = (const int*)d_in[27]; const int* iu0_c = (const int*)d_in[28];
    const float* iu0_v = (const float*)d_in[29];
    const float* d_i_1 = (const float*)d_in[30];
    const float* d_j_1 = (const float*)d_in[31];
    const float* d_i_0 = (const float*)d_in[32];
    const float* d_j_0 = (const float*)d_in[33];
    float* out = (float*)d_out;

    typedef unsigned short u16;
    char* p = (char*)d_ws;
    size_t off = 0;
    auto alloc = [&](size_t bytes) { char* q = p + off; off += align256(bytes); return q; };
    // bf16 state
    u16* stat  = (u16*)alloc(size_t(SN) * KN * 2);
    u16* kdiff = (u16*)alloc(size_t(EN) * KN * 2);
    // aggregation buffers
    u16* as1 = (u16*)alloc(size_t(SN) * KN * 2);
    u16* as0 = (u16*)alloc(size_t(SN) * KN * 2);
    u16* ae1 = (u16*)alloc(size_t(EN) * KN * 2);
    u16* ae0 = (u16*)alloc(size_t(EN) * KN * 2);
    // bf16 weight tables
    u16* Kb  = (u16*)alloc(size_t(KN) * DN * 2);
    u16* Wb1 = (u16*)alloc(size_t(KN) * KN * 2);
    u16* Wb0 = (u16*)alloc(size_t(KN) * KN * 2);
    // sort structures
    int*  coarseCnt  = (int*)alloc(256 * 4);
    int*  coarseBase = (int*)alloc(257 * 4);
    int*  tails      = (int*)alloc(256 * 4);
    int*  rp_all     = (int*)alloc(size_t(NTOT + 1) * 4);
    int2* stg        = (int2*)alloc(size_t(4) * NE * 8);
    int2* cv_all     = (int2*)alloc(size_t(4) * NE * 8);
    // head
    float* xh = (float*)alloc(size_t(BN) * KN * 4);
    float* h1 = (float*)alloc(size_t(BN) * 256 * 4);
    float* h2 = (float*)alloc(size_t(BN) * 128 * 4);
    if (off > ws_size) return;

    CsrB c;
    c.rows[0] = ui1_r; c.cols[0] = ui1_c; c.vals[0] = ui1_v;
    c.rows[1] = ui0_r; c.cols[1] = ui0_c; c.vals[1] = ui0_v;
    c.rows[2] = iu1_r; c.cols[2] = iu1_c; c.vals[2] = iu1_v;
    c.rows[3] = iu0_r; c.cols[3] = iu0_c; c.vals[3] = iu0_v;

    // ---- two-pass partition sort ----
    hipMemsetAsync(coarseCnt, 0, 256 * 4, stream);
    hist_coarse<<<4 * HB, 256, 0, stream>>>(c, coarseCnt);
    scan_coarse<<<1, 256, 0, stream>>>(coarseCnt, coarseBase, tails);
    part1<<<4 * PG1, 512, 0, stream>>>(c, tails, stg);
    part2<<<NBIN, 512, 0, stream>>>(coarseBase, stg, rp_all, cv_all);

    // ---- bf16 weight conversions ----
    f2bf<<<(KN * DN / 2 + 255) / 256, 256, 0, stream>>>(kn_base, Kb, KN * DN / 2);
    f2bf<<<(KN * KN / 2 + 255) / 256, 256, 0, stream>>>(W1_w, Wb1, KN * KN / 2);
    f2bf<<<(KN * KN / 2 + 255) / 256, 256, 0, stream>>>(W0_w, Wb0, KN * KN / 2);

    // ---- projections (read f32 embeddings directly) ----
    gemm_proj<DN><<<(SN + 63) / 64, 256, 0, stream>>>(stu_emb, Kb, stat, SN);
    gemm_proj<DN><<<(EN + 63) / 64, 256, 0, stream>>>(exer_emb, Kb, kdiff, EN);

    // ---- GCN layers: merged aggregate, then dual-weight projection ----
    for (int l = 0; l < NLAYER; ++l) {
        spmm_all<<<(SN + EN + 3) / 4, 256, 0, stream>>>(
            rp_all, (const long long*)cv_all, kdiff, stat, as1, as0, ae1, ae0);
        gemm2_mfma<<<(SN + 63) / 64, 256, 0, stream>>>(
            as1, as0, stat, d_i_1, d_i_0, Wb1, Wb0, W1_b, W0_b, stat, SN);
        gemm2_mfma<<<(EN + 63) / 64, 256, 0, stream>>>(
            ae1, ae0, kdiff, d_j_1, d_j_0, Wb1, Wb0, W1_b, W0_b, kdiff, EN);
    }

    // ---- head ----
    head1_kernel<<<BN, 128, 0, stream>>>(stu_id, exer_id, kn_emb, stat, kdiff,
                                         stu_bias, e_disc, xh);
    gemm_xwT<128, 256, 16, true, true><<<BN / 16, 256, 0, stream>>>(xh, pn1_w, pn1_b, h1, BN);
    gemm_xwT<256, 128, 32, true, true><<<BN / 32, 256, 0, stream>>>(h1, pn2_w, pn2_b, h2, BN);
    pn3_kernel<<<BN / 256, 256, 0, stream>>>(h2, pn3_w, pn3_b, out);
    (void)out_size; (void)n_in; (void)in_sizes;
}

// Round 8
// 850.943 us; speedup vs baseline: 1.0174x; 1.0174x over previous
//
#include <hip/hip_runtime.h>
#include <hip/hip_bf16.h>

// Problem constants (from reference)
#define SN 50000
#define EN 20000
#define KN 128
#define DN 64
#define BN 4096
#define NE 1000000
#define NLAYER 3

// Column-chunk bucketing: chunk = 4096 gather-table rows (fp8: 0.5MB)
#define CH_SHIFT 12
#define NCH0 5                        // side0 (ui): cols index kdiff, EN -> 5 chunks
#define NCH1 13                       // side1 (iu): cols index stat,  SN -> 13 chunks
#define SIDE1_BASE (SN * NCH0)        // 250000
#define NTOT (SN * NCH0 + EN * NCH1)  // 510000 fine buckets

// Two-pass partition sort
#define BIN_SHIFT 11
#define NBIN ((NTOT + 2047) >> 11)    // 250 coarse bins (2048 fine buckets each)
#define T1 4096                       // edges per part1 tile
#define PG1 ((NE + T1 - 1) / T1)      // 245 tiles per adjacency
#define HB 256                        // hist blocks per adjacency

typedef float f32x4 __attribute__((ext_vector_type(4)));
typedef float f32x2 __attribute__((ext_vector_type(2)));
typedef short bf16x8 __attribute__((ext_vector_type(8)));

__device__ __forceinline__ float sigmoidf_(float v) { return 1.f / (1.f + __expf(-v)); }
__device__ __forceinline__ float bf_lo(unsigned u) { return __uint_as_float(u << 16); }
__device__ __forceinline__ float bf_hi(unsigned u) { return __uint_as_float(u & 0xffff0000u); }
__device__ __forceinline__ float bf_one(unsigned short s) { return __uint_as_float((unsigned)s << 16); }
__device__ __forceinline__ unsigned packbf2(float a, float b) {
    __hip_bfloat16 ha = __float2bfloat16(a), hb = __float2bfloat16(b);
    unsigned short ua = *(unsigned short*)&ha, ub = *(unsigned short*)&hb;
    return (unsigned)ua | ((unsigned)ub << 16);
}
__device__ __forceinline__ unsigned short packbf1(float a) {
    __hip_bfloat16 ha = __float2bfloat16(a);
    return *(unsigned short*)&ha;
}

struct CsrB {
    const int* rows[4]; const int* cols[4]; const float* vals[4];
};

// ---------------------------------------------------------------------------
// Coarse histogram (250 bins), LDS-staged
// ---------------------------------------------------------------------------
__global__ __launch_bounds__(256) void hist_coarse(CsrB c, int* __restrict__ cnt) {
    __shared__ int h[256];
    const int t = threadIdx.x;
    h[t] = 0;
    __syncthreads();
    const int a = blockIdx.x >> 8;
    const int tile = blockIdx.x & 255;
    const int per = (NE + HB - 1) / HB;
    const int beg = tile * per, end = min(beg + per, NE);
    const int side = a >> 1;
    const int nch = side ? NCH1 : NCH0;
    const int basebk = side ? SIDE1_BASE : 0;
    for (int i = beg + t; i < end; i += 256) {
        int B = basebk + c.rows[a][i] * nch + (c.cols[a][i] >> CH_SHIFT);
        atomicAdd(&h[B >> BIN_SHIFT], 1);
    }
    __syncthreads();
    if (h[t]) atomicAdd(&cnt[t], h[t]);
}

// 1-block exclusive scan of 256 coarse counts -> base[257] and tails[256]
__global__ __launch_bounds__(256) void scan_coarse(const int* __restrict__ cnt,
                                                   int* __restrict__ base,
                                                   int* __restrict__ tails) {
    __shared__ int sh[256];
    const int t = threadIdx.x;
    const int v = cnt[t];
    sh[t] = v;
    __syncthreads();
    for (int o = 1; o < 256; o <<= 1) {
        int x = sh[t]; int u = (t >= o) ? sh[t - o] : 0;
        __syncthreads(); sh[t] = x + u; __syncthreads();
    }
    const int ex = sh[t] - v;
    base[t] = ex;
    tails[t] = ex;
    if (t == 255) base[256] = sh[255];
}

// ---------------------------------------------------------------------------
// part1: multisplit edges into coarse-bin segments with coalesced writes.
// Record int2: .x = col(0..15) | fine_bucket_low11(17..27)
//              .y = f32 val, SIGN-ENCODED: negative <=> neg-adjacency (tag 0)
// ---------------------------------------------------------------------------
__global__ __launch_bounds__(512) void part1(CsrB c, int* __restrict__ tails,
                                             int2* __restrict__ stg) {
    __shared__ int2 srec[T1];
    __shared__ unsigned char sbin[T1];
    __shared__ int h[256], offs[256], gbase[256], sc[512];
    const int t = threadIdx.x;
    const int a = blockIdx.x / PG1;
    const int tile = blockIdx.x - a * PG1;
    const int beg = tile * T1;
    const int cnt = min(T1, NE - beg);
    if (t < 256) h[t] = 0;
    __syncthreads();

    int2 rec[8]; int rbin[8]; int rrank[8];
    const int side = a >> 1;
    const int nch = side ? NCH1 : NCH0;
    const int basebk = side ? SIDE1_BASE : 0;
    const float sgn = (a & 1) ? -1.f : 1.f;  // a=0,2: pos(tag1); a=1,3: neg(tag0)
#pragma unroll
    for (int k = 0; k < 8; ++k) {
        int o = t + k * 512;
        if (o < cnt) {
            int i = beg + o;
            int cc = c.cols[a][i];
            int B = basebk + c.rows[a][i] * nch + (cc >> CH_SHIFT);
            int bin = B >> BIN_SHIFT;
            rec[k] = make_int2(cc | ((B & 2047) << 17),
                               __float_as_int(sgn * c.vals[a][i]));
            rbin[k] = bin;
            rrank[k] = atomicAdd(&h[bin], 1);
        } else {
            rbin[k] = -1;
        }
    }
    __syncthreads();
    sc[t] = (t < 256) ? h[t] : 0;
    __syncthreads();
    for (int o = 1; o < 256; o <<= 1) {
        int x = sc[t]; int u = (t >= o) ? sc[t - o] : 0;
        __syncthreads(); sc[t] = x + u; __syncthreads();
    }
    if (t < 256) {
        offs[t] = sc[t] - h[t];
        if (h[t] > 0) gbase[t] = atomicAdd(&tails[t], h[t]);
    }
    __syncthreads();
#pragma unroll
    for (int k = 0; k < 8; ++k) {
        if (rbin[k] >= 0) {
            int pos = offs[rbin[k]] + rrank[k];
            srec[pos] = rec[k];
            sbin[pos] = (unsigned char)rbin[k];
        }
    }
    __syncthreads();
    for (int idx = t; idx < cnt; idx += 512) {
        int b = sbin[idx];
        stg[gbase[b] + (idx - offs[b])] = srec[idx];
    }
}

// ---------------------------------------------------------------------------
// part2: one block per coarse bin. Builds fine histogram+prefix in LDS
// (producing rp_all), then scatters into the bin's own ~128KB window.
// cv record: .x = bare column, .y = sign-encoded f32 value
// ---------------------------------------------------------------------------
__global__ __launch_bounds__(512) void part2(const int* __restrict__ coarseBase,
                                             const int2* __restrict__ stg,
                                             int* __restrict__ rp,
                                             int2* __restrict__ cv) {
    __shared__ int cnt2[2048];
    __shared__ int tsum[512];
    const int b = blockIdx.x;
    const int t = threadIdx.x;
    const int fineBase = b << BIN_SHIFT;
    const int nf = min(2048, NTOT - fineBase);
    const int segBeg = coarseBase[b];
    const int segEnd = coarseBase[b + 1];
    for (int i = t; i < 2048; i += 512) cnt2[i] = 0;
    __syncthreads();
    for (int e = segBeg + t; e < segEnd; e += 512)
        atomicAdd(&cnt2[((unsigned)stg[e].x) >> 17], 1);
    __syncthreads();
    const int i4 = t * 4;
    int v0 = cnt2[i4], v1 = cnt2[i4 + 1], v2 = cnt2[i4 + 2], v3 = cnt2[i4 + 3];
    tsum[t] = v0 + v1 + v2 + v3;
    __syncthreads();
    for (int o = 1; o < 512; o <<= 1) {
        int x = tsum[t]; int u = (t >= o) ? tsum[t - o] : 0;
        __syncthreads(); tsum[t] = x + u; __syncthreads();
    }
    const int pre = (t == 0) ? 0 : tsum[t - 1];
    const int p0 = pre, p1 = pre + v0, p2 = p1 + v1, p3 = p2 + v2;
    cnt2[i4] = p0; cnt2[i4 + 1] = p1; cnt2[i4 + 2] = p2; cnt2[i4 + 3] = p3;
    if (i4 + 0 < nf) rp[fineBase + i4 + 0] = segBeg + p0;
    if (i4 + 1 < nf) rp[fineBase + i4 + 1] = segBeg + p1;
    if (i4 + 2 < nf) rp[fineBase + i4 + 2] = segBeg + p2;
    if (i4 + 3 < nf) rp[fineBase + i4 + 3] = segBeg + p3;
    if (b == NBIN - 1 && t == 511) rp[NTOT] = segEnd;
    __syncthreads();
    for (int e = segBeg + t; e < segEnd; e += 512) {
        int2 r = stg[e];
        int pos = segBeg + atomicAdd(&cnt2[((unsigned)r.x) >> 17], 1);
        cv[pos] = make_int2(r.x & 0xFFFF, r.y);
    }
}

// ---------------------------------------------------------------------------
// fp32 -> bf16 conversion (small weight tables only)
// ---------------------------------------------------------------------------
__global__ __launch_bounds__(256) void f2bf(const float* __restrict__ src,
                                            unsigned short* __restrict__ dst, int n2) {
    int i = blockIdx.x * 256 + threadIdx.x;
    if (i < n2) {
        float2 f = ((const float2*)src)[i];
        ((unsigned*)dst)[i] = packbf2(f.x, f.y);
    }
}

// ---------------------------------------------------------------------------
// bf16 -> fp8 e4m3 shadow conversion (4 elems/thread)
// ---------------------------------------------------------------------------
__global__ __launch_bounds__(256) void bf2fp8(const unsigned* __restrict__ src,
                                              unsigned* __restrict__ dst, int n4) {
    int i = blockIdx.x * 256 + threadIdx.x;
    if (i < n4) {
        unsigned a = src[2 * i], b = src[2 * i + 1];
        float f0 = bf_lo(a), f1 = bf_hi(a), f2 = bf_lo(b), f3 = bf_hi(b);
        int pk = __builtin_amdgcn_cvt_pk_fp8_f32(f0, f1, 0, false);
        pk = __builtin_amdgcn_cvt_pk_fp8_f32(f2, f3, pk, true);
        dst[i] = (unsigned)pk;
    }
}

// ---------------------------------------------------------------------------
// Projection MFMA GEMM: out[M,128](bf16) = X[M,KK](f32) @ W[128,KK]^T(bf16)
// ---------------------------------------------------------------------------
template <int KK>
__global__ __launch_bounds__(256) void gemm_proj(const float* __restrict__ X,
                                                 const unsigned short* __restrict__ W,
                                                 unsigned short* __restrict__ out, int M) {
    constexpr int PITCH = KK + 8;
    __shared__ unsigned short Wl[128 * PITCH];
    const int t = threadIdx.x;
    for (int idx = t * 8; idx < 128 * KK; idx += 2048) {
        int r = idx / KK, k = idx - r * KK;
        *(uint4*)(&Wl[r * PITCH + k]) = *(const uint4*)(&W[idx]);
    }
    __syncthreads();
    const int lane = t & 63;
    const int nm = lane & 15;
    const int quad = lane >> 4;
    const int row0 = blockIdx.x * 64 + (t >> 6) * 16;
    if (row0 >= M) return;

    f32x4 acc[8];
#pragma unroll
    for (int nt = 0; nt < 8; ++nt) acc[nt] = (f32x4){0.f, 0.f, 0.f, 0.f};

    const float* xrow = X + (size_t)(row0 + nm) * KK + quad * 8;
#pragma unroll
    for (int ks = 0; ks < KK / 32; ++ks) {
        float4 f0 = *(const float4*)(xrow + ks * 32);
        float4 f1 = *(const float4*)(xrow + ks * 32 + 4);
        unsigned q[4] = {packbf2(f0.x, f0.y), packbf2(f0.z, f0.w),
                         packbf2(f1.x, f1.y), packbf2(f1.z, f1.w)};
        bf16x8 a = *(bf16x8*)q;
#pragma unroll
        for (int nt = 0; nt < 8; ++nt) {
            bf16x8 b = *(const bf16x8*)(&Wl[(nt * 16 + nm) * PITCH + ks * 32 + quad * 8]);
            acc[nt] = __builtin_amdgcn_mfma_f32_16x16x32_bf16(a, b, acc[nt], 0, 0, 0);
        }
    }
    unsigned short* orow = out + (size_t)(row0 + quad * 4) * 128 + nm;
#pragma unroll
    for (int r = 0; r < 4; ++r)
#pragma unroll
        for (int nt = 0; nt < 8; ++nt)
            orow[(size_t)r * 128 + nt * 16] = packbf1(acc[nt][r]);
}

// ---------------------------------------------------------------------------
// Fused dual-weight MFMA GEMM, BOTH sides in one dispatch (in-place safe):
//   out = (agg1 + d1.*y)@W1^T + (agg0 + d0.*y)@W0^T + (b1+b0)
// ---------------------------------------------------------------------------
__global__ __launch_bounds__(256) void gemm2_mfma(
    const unsigned short* __restrict__ agg1S, const unsigned short* __restrict__ agg0S,
    const unsigned short* __restrict__ yS,
    const float* __restrict__ d1S, const float* __restrict__ d0S,
    unsigned short* __restrict__ outS,
    const unsigned short* __restrict__ agg1E, const unsigned short* __restrict__ agg0E,
    const unsigned short* __restrict__ yE,
    const float* __restrict__ d1E, const float* __restrict__ d0E,
    unsigned short* __restrict__ outE,
    const unsigned short* __restrict__ W1, const unsigned short* __restrict__ W0,
    const float* __restrict__ b1, const float* __restrict__ b0, int nblkS) {
    constexpr int PITCH = 136;
    __shared__ unsigned short Wl[2 * 128 * PITCH];
    const int t = threadIdx.x;
    for (int idx = t * 8; idx < 128 * 128; idx += 2048) {
        int r = idx >> 7, k = idx & 127;
        *(uint4*)(&Wl[r * PITCH + k]) = *(const uint4*)(&W1[idx]);
        *(uint4*)(&Wl[128 * PITCH + r * PITCH + k]) = *(const uint4*)(&W0[idx]);
    }
    __syncthreads();
    const bool sideE = (int)blockIdx.x >= nblkS;
    const unsigned short* agg1 = sideE ? agg1E : agg1S;
    const unsigned short* agg0 = sideE ? agg0E : agg0S;
    const unsigned short* y    = sideE ? yE : yS;
    const float* d1 = sideE ? d1E : d1S;
    const float* d0 = sideE ? d0E : d0S;
    unsigned short* out = sideE ? outE : outS;
    const int M = sideE ? EN : SN;
    const int lane = t & 63;
    const int nm = lane & 15;
    const int quad = lane >> 4;
    const int row0 = ((int)blockIdx.x - (sideE ? nblkS : 0)) * 64 + (t >> 6) * 16;
    if (row0 >= M) return;

    const float d1v = d1[row0 + nm];
    const float d0v = d0[row0 + nm];

    f32x4 acc[8];
#pragma unroll
    for (int nt = 0; nt < 8; ++nt) acc[nt] = (f32x4){0.f, 0.f, 0.f, 0.f};

    const size_t rbase = (size_t)(row0 + nm) * 128 + quad * 8;
#pragma unroll
    for (int ks = 0; ks < 4; ++ks) {
        uint4 ua1 = *(const uint4*)(agg1 + rbase + ks * 32);
        uint4 ua0 = *(const uint4*)(agg0 + rbase + ks * 32);
        uint4 uy  = *(const uint4*)(y    + rbase + ks * 32);
        uint4 p1, p0;
        {
            unsigned* a1 = (unsigned*)&ua1; unsigned* a0 = (unsigned*)&ua0;
            unsigned* yy = (unsigned*)&uy;
            unsigned* q1 = (unsigned*)&p1; unsigned* q0 = (unsigned*)&p0;
#pragma unroll
            for (int w = 0; w < 4; ++w) {
                float ylo = bf_lo(yy[w]), yhi = bf_hi(yy[w]);
                q1[w] = packbf2(bf_lo(a1[w]) + d1v * ylo, bf_hi(a1[w]) + d1v * yhi);
                q0[w] = packbf2(bf_lo(a0[w]) + d0v * ylo, bf_hi(a0[w]) + d0v * yhi);
            }
        }
        bf16x8 af1 = *(bf16x8*)&p1;
        bf16x8 af0 = *(bf16x8*)&p0;
#pragma unroll
        for (int nt = 0; nt < 8; ++nt) {
            bf16x8 bw1 = *(const bf16x8*)(&Wl[(nt * 16 + nm) * PITCH + ks * 32 + quad * 8]);
            acc[nt] = __builtin_amdgcn_mfma_f32_16x16x32_bf16(af1, bw1, acc[nt], 0, 0, 0);
            bf16x8 bw0 = *(const bf16x8*)(&Wl[128 * PITCH + (nt * 16 + nm) * PITCH + ks * 32 + quad * 8]);
            acc[nt] = __builtin_amdgcn_mfma_f32_16x16x32_bf16(af0, bw0, acc[nt], 0, 0, 0);
        }
    }
    unsigned short* orow = out + (size_t)(row0 + quad * 4) * 128 + nm;
#pragma unroll
    for (int nt = 0; nt < 8; ++nt) {
        float bb = b1[nt * 16 + nm] + b0[nt * 16 + nm];
#pragma unroll
        for (int r = 0; r < 4; ++r)
            orow[(size_t)r * 128 + nt * 16] = packbf1(acc[nt][r] + bb);
    }
}

// ---------------------------------------------------------------------------
// Merged dual SPMM, both sides, fp8 gather tables. Sign-encoded tag:
//   all += |v|*g ; pos += max(v,0)*g ; neg = all - pos.
// Wave per row; lane owns cols 2l,2l+1 via one u16 (2 fp8) gather +
// v_cvt_pk_f32_fp8 unpack. Edge records as raw 64-bit ints.
// ---------------------------------------------------------------------------
__global__ __launch_bounds__(256) void spmm_all(
    const int* __restrict__ rp, const long long* __restrict__ cv,
    const unsigned char* __restrict__ kd8, const unsigned char* __restrict__ st8,
    unsigned short* __restrict__ as1, unsigned short* __restrict__ as0,
    unsigned short* __restrict__ ae1, unsigned short* __restrict__ ae0) {
    const int wave = (blockIdx.x * 256 + threadIdx.x) >> 6;
    const int lane = threadIdx.x & 63;
    if (wave >= SN + EN) return;
    const bool sideE = wave >= SN;
    const int r = sideE ? wave - SN : wave;
    const int nch = sideE ? NCH1 : NCH0;
    const int* rpb = sideE ? (rp + SIDE1_BASE) : rp;
    const unsigned char* g8 = (sideE ? st8 : kd8) + lane * 2;
    unsigned short* o1 = sideE ? ae1 : as1;
    unsigned short* o0 = sideE ? ae0 : as0;

    float aAlo = 0.f, aAhi = 0.f, aPlo = 0.f, aPhi = 0.f;
    int e = rpb[r * nch];
    const int ee = rpb[(r + 1) * nch];

#define BODY(E, U)                                                          \
    {                                                                       \
        float sv = __int_as_float((int)((E) >> 32));                        \
        float v = fabsf(sv);                                                \
        float v1 = fmaxf(sv, 0.f);                                          \
        f32x2 gg = __builtin_amdgcn_cvt_pk_f32_fp8((int)(unsigned)(U), false); \
        aAlo += v * gg.x; aAhi += v * gg.y;                                 \
        aPlo += v1 * gg.x; aPhi += v1 * gg.y;                               \
    }
    for (; e + 8 <= ee; e += 8) {
        long long E0 = __builtin_nontemporal_load(&cv[e]);
        long long E1 = __builtin_nontemporal_load(&cv[e + 1]);
        long long E2 = __builtin_nontemporal_load(&cv[e + 2]);
        long long E3 = __builtin_nontemporal_load(&cv[e + 3]);
        long long E4 = __builtin_nontemporal_load(&cv[e + 4]);
        long long E5 = __builtin_nontemporal_load(&cv[e + 5]);
        long long E6 = __builtin_nontemporal_load(&cv[e + 6]);
        long long E7 = __builtin_nontemporal_load(&cv[e + 7]);
        unsigned short u0 = *(const unsigned short*)(g8 + ((((int)E0) & 0xFFFF) << 7));
        unsigned short u1 = *(const unsigned short*)(g8 + ((((int)E1) & 0xFFFF) << 7));
        unsigned short u2 = *(const unsigned short*)(g8 + ((((int)E2) & 0xFFFF) << 7));
        unsigned short u3 = *(const unsigned short*)(g8 + ((((int)E3) & 0xFFFF) << 7));
        unsigned short u4 = *(const unsigned short*)(g8 + ((((int)E4) & 0xFFFF) << 7));
        unsigned short u5 = *(const unsigned short*)(g8 + ((((int)E5) & 0xFFFF) << 7));
        unsigned short u6 = *(const unsigned short*)(g8 + ((((int)E6) & 0xFFFF) << 7));
        unsigned short u7 = *(const unsigned short*)(g8 + ((((int)E7) & 0xFFFF) << 7));
        BODY(E0, u0) BODY(E1, u1) BODY(E2, u2) BODY(E3, u3)
        BODY(E4, u4) BODY(E5, u5) BODY(E6, u6) BODY(E7, u7)
    }
    for (; e < ee; ++e) {
        long long E0 = __builtin_nontemporal_load(&cv[e]);
        unsigned short u0 = *(const unsigned short*)(g8 + ((((int)E0) & 0xFFFF) << 7));
        BODY(E0, u0)
    }
#undef BODY
    const int base = (r << 7) + lane * 2;
    *(unsigned*)&o1[base] = packbf2(aPlo, aPhi);
    *(unsigned*)&o0[base] = packbf2(aAlo - aPlo, aAhi - aPhi);
}

// ---------------------------------------------------------------------------
// fp32 tiled GEMM for the head: out = act( X @ |W|^T + b )
// ---------------------------------------------------------------------------
template <int KK, int NCOLS, int ROWS, bool ABSW, bool SIG>
__global__ __launch_bounds__(256) void gemm_xwT(const float* __restrict__ X,
                                                const float* __restrict__ W,
                                                const float* __restrict__ bias,
                                                float* __restrict__ out, int M) {
    constexpr int KP = 32;
    constexpr int NG = 256 / NCOLS;
    constexpr int RT = ROWS / NG;
    __shared__ float BT[KP * (NCOLS + 1)];
    __shared__ float Xl[ROWS * (KK + 1)];
    const int t = threadIdx.x;
    const int j = t % NCOLS;
    const int rg = t / NCOLS;
    const int row0 = blockIdx.x * ROWS;

    for (int idx = t; idx < ROWS * KK; idx += 256) {
        int r = idx / KK, k = idx % KK;
        int gr = row0 + r;
        Xl[r * (KK + 1) + k] = (gr < M) ? X[gr * KK + k] : 0.f;
    }
    float acc[RT];
#pragma unroll
    for (int i = 0; i < RT; ++i) acc[i] = 0.f;

    for (int k0 = 0; k0 < KK; k0 += KP) {
        __syncthreads();
        for (int idx = t; idx < NCOLS * KP; idx += 256) {
            int jj = idx / KP, kp = idx % KP;
            float w = W[jj * KK + k0 + kp];
            BT[kp * (NCOLS + 1) + jj] = ABSW ? fabsf(w) : w;
        }
        __syncthreads();
#pragma unroll
        for (int kp = 0; kp < KP; ++kp) {
            float b = BT[kp * (NCOLS + 1) + j];
#pragma unroll
            for (int rr = 0; rr < RT; ++rr)
                acc[rr] += Xl[(rg * RT + rr) * (KK + 1) + k0 + kp] * b;
        }
    }
    float bj = bias ? bias[j] : 0.f;
#pragma unroll
    for (int rr = 0; rr < RT; ++rr) {
        int gr = row0 + rg * RT + rr;
        if (gr < M) {
            float v = acc[rr] + bj;
            out[gr * NCOLS + j] = SIG ? sigmoidf_(v) : v;
        }
    }
}

// ---------------------------------------------------------------------------
// Head kernels
// ---------------------------------------------------------------------------
__global__ __launch_bounds__(128) void head1_kernel(
    const int* __restrict__ stu_id, const int* __restrict__ exer_id,
    const float* __restrict__ kn_emb, const unsigned short* __restrict__ stat,
    const unsigned short* __restrict__ kdiff, const float* __restrict__ stu_bias,
    const float* __restrict__ e_disc, float* __restrict__ x) {
    const int b = blockIdx.x;
    const int k = threadIdx.x;
    const int sid = stu_id[b], eid = exer_id[b];
    float disc = sigmoidf_(e_disc[eid]);
    float sb = sigmoidf_(bf_one(stat[(sid << 7) + k]) + stu_bias[sid]);
    float kd = sigmoidf_(bf_one(kdiff[(eid << 7) + k]));
    x[(b << 7) + k] = disc * (sb - kd) * kn_emb[(b << 7) + k];
}

__global__ __launch_bounds__(256) void pn3_kernel(const float* __restrict__ h2,
                                                  const float* __restrict__ w3,
                                                  const float* __restrict__ b3,
                                                  float* __restrict__ out) {
    __shared__ float wl[128];
    const int t = threadIdx.x;
    if (t < 128) wl[t] = fabsf(w3[t]);
    __syncthreads();
    const int b = blockIdx.x * 256 + t;
    float acc = 0.f;
#pragma unroll 4
    for (int k = 0; k < 128; ++k) acc += h2[(b << 7) + k] * wl[k];
    out[b] = sigmoidf_(acc + b3[0]);
}

// ---------------------------------------------------------------------------
// Launch
// ---------------------------------------------------------------------------
static inline size_t align256(size_t x) { return (x + 255) & ~size_t(255); }

extern "C" void kernel_launch(void* const* d_in, const int* in_sizes, int n_in,
                              void* d_out, int out_size, void* d_ws, size_t ws_size,
                              hipStream_t stream) {
    const int*   stu_id   = (const int*)d_in[0];
    const int*   exer_id  = (const int*)d_in[1];
    const float* kn_emb   = (const float*)d_in[2];
    const float* stu_emb  = (const float*)d_in[3];
    const float* exer_emb = (const float*)d_in[4];
    const float* kn_base  = (const float*)d_in[5];
    const float* stu_bias = (const float*)d_in[6];
    const float* e_disc   = (const float*)d_in[7];
    const float* W1_w     = (const float*)d_in[8];
    const float* W1_b     = (const float*)d_in[9];
    const float* W0_w     = (const float*)d_in[10];
    const float* W0_b     = (const float*)d_in[11];
    const float* pn1_w    = (const float*)d_in[12];
    const float* pn1_b    = (const float*)d_in[13];
    const float* pn2_w    = (const float*)d_in[14];
    const float* pn2_b    = (const float*)d_in[15];
    const float* pn3_w    = (const float*)d_in[16];
    const float* pn3_b    = (const float*)d_in[17];
    const int*   ui1_r = (const int*)d_in[18]; const int* ui1_c = (const int*)d_in[19];
    const float* ui1_v = (const float*)d_in[20];
    const int*   iu1_r = (const int*)d_in[21]; const int* iu1_c = (const int*)d_in[22];
    const float* iu1_v = (const float*)d_in[23];
    const int*   ui0_r = (const int*)d_in[24]; const int* ui0_c = (const int*)d_in[25];
    const float* ui0_v = (const float*)d_in[26];
    const int*   iu0_r = (const int*)d_in[27]; const int* iu0_c = (const int*)d_in[28];
    const float* iu0_v = (const float*)d_in[29];
    const float* d_i_1 = (const float*)d_in[30];
    const float* d_j_1 = (const float*)d_in[31];
    const float* d_i_0 = (const float*)d_in[32];
    const float* d_j_0 = (const float*)d_in[33];
    float* out = (float*)d_out;

    typedef unsigned short u16;
    typedef unsigned char u8;
    char* p = (char*)d_ws;
    size_t off = 0;
    auto alloc = [&](size_t bytes) { char* q = p + off; off += align256(bytes); return q; };
    // bf16 state — stat & kdiff allocated CONTIGUOUSLY (bf2fp8 spans both)
    u16* stat  = (u16*)alloc(size_t(SN) * KN * 2);   // 12,800,000 B (256-mult)
    u16* kdiff = (u16*)alloc(size_t(EN) * KN * 2);   // immediately after
    // fp8 shadows — also contiguous pair
    u8* st8 = (u8*)alloc(size_t(SN) * KN);           // 6,400,000 B (256-mult)
    u8* kd8 = (u8*)alloc(size_t(EN) * KN);           // immediately after
    // aggregation buffers
    u16* as1 = (u16*)alloc(size_t(SN) * KN * 2);
    u16* as0 = (u16*)alloc(size_t(SN) * KN * 2);
    u16* ae1 = (u16*)alloc(size_t(EN) * KN * 2);
    u16* ae0 = (u16*)alloc(size_t(EN) * KN * 2);
    // bf16 weight tables
    u16* Kb  = (u16*)alloc(size_t(KN) * DN * 2);
    u16* Wb1 = (u16*)alloc(size_t(KN) * KN * 2);
    u16* Wb0 = (u16*)alloc(size_t(KN) * KN * 2);
    // sort structures
    int*  coarseCnt  = (int*)alloc(256 * 4);
    int*  coarseBase = (int*)alloc(257 * 4);
    int*  tails      = (int*)alloc(256 * 4);
    int*  rp_all     = (int*)alloc(size_t(NTOT + 1) * 4);
    int2* stg        = (int2*)alloc(size_t(4) * NE * 8);
    int2* cv_all     = (int2*)alloc(size_t(4) * NE * 8);
    // head
    float* xh = (float*)alloc(size_t(BN) * KN * 4);
    float* h1 = (float*)alloc(size_t(BN) * 256 * 4);
    float* h2 = (float*)alloc(size_t(BN) * 128 * 4);
    if (off > ws_size) return;

    CsrB c;
    c.rows[0] = ui1_r; c.cols[0] = ui1_c; c.vals[0] = ui1_v;
    c.rows[1] = ui0_r; c.cols[1] = ui0_c; c.vals[1] = ui0_v;
    c.rows[2] = iu1_r; c.cols[2] = iu1_c; c.vals[2] = iu1_v;
    c.rows[3] = iu0_r; c.cols[3] = iu0_c; c.vals[3] = iu0_v;

    // ---- two-pass partition sort ----
    hipMemsetAsync(coarseCnt, 0, 256 * 4, stream);
    hist_coarse<<<4 * HB, 256, 0, stream>>>(c, coarseCnt);
    scan_coarse<<<1, 256, 0, stream>>>(coarseCnt, coarseBase, tails);
    part1<<<4 * PG1, 512, 0, stream>>>(c, tails, stg);
    part2<<<NBIN, 512, 0, stream>>>(coarseBase, stg, rp_all, cv_all);

    // ---- bf16 weight conversions ----
    f2bf<<<(KN * DN / 2 + 255) / 256, 256, 0, stream>>>(kn_base, Kb, KN * DN / 2);
    f2bf<<<(KN * KN / 2 + 255) / 256, 256, 0, stream>>>(W1_w, Wb1, KN * KN / 2);
    f2bf<<<(KN * KN / 2 + 255) / 256, 256, 0, stream>>>(W0_w, Wb0, KN * KN / 2);

    // ---- projections (read f32 embeddings directly) ----
    gemm_proj<DN><<<(SN + 63) / 64, 256, 0, stream>>>(stu_emb, Kb, stat, SN);
    gemm_proj<DN><<<(EN + 63) / 64, 256, 0, stream>>>(exer_emb, Kb, kdiff, EN);

    const int N4 = (SN + EN) * KN / 4;   // fp8-shadow conversion span (both tables)
    const int nblkS = (SN + 63) / 64, nblkE = (EN + 63) / 64;

    // ---- GCN layers ----
    for (int l = 0; l < NLAYER; ++l) {
        bf2fp8<<<(N4 + 255) / 256, 256, 0, stream>>>((const unsigned*)stat,
                                                     (unsigned*)st8, N4);
        spmm_all<<<(SN + EN + 3) / 4, 256, 0, stream>>>(
            rp_all, (const long long*)cv_all, kd8, st8, as1, as0, ae1, ae0);
        gemm2_mfma<<<nblkS + nblkE, 256, 0, stream>>>(
            as1, as0, stat, d_i_1, d_i_0, stat,
            ae1, ae0, kdiff, d_j_1, d_j_0, kdiff,
            Wb1, Wb0, W1_b, W0_b, nblkS);
    }

    // ---- head ----
    head1_kernel<<<BN, 128, 0, stream>>>(stu_id, exer_id, kn_emb, stat, kdiff,
                                         stu_bias, e_disc, xh);
    gemm_xwT<128, 256, 16, true, true><<<BN / 16, 256, 0, stream>>>(xh, pn1_w, pn1_b, h1, BN);
    gemm_xwT<256, 128, 32, true, true><<<BN / 32, 256, 0, stream>>>(h1, pn2_w, pn2_b, h2, BN);
    pn3_kernel<<<BN / 256, 256, 0, stream>>>(h2, pn3_w, pn3_b, out);
    (void)out_size; (void)n_in; (void)in_sizes;
}

// Round 9
// 736.365 us; speedup vs baseline: 1.1757x; 1.1556x over previous
//
#include <hip/hip_runtime.h>
#include <hip/hip_bf16.h>

// Problem constants (from reference)
#define SN 50000
#define EN 20000
#define KN 128
#define DN 64
#define BN 4096
#define NE 1000000
#define NLAYER 3

// Column-chunk bucketing: chunk = 4096 gather-table rows (fp8: 0.5MB)
#define CH_SHIFT 12
#define NCH0 5                        // side0 (ui): cols index kdiff, EN -> 5 chunks
#define NCH1 13                       // side1 (iu): cols index stat,  SN -> 13 chunks
// fine bucket = (2*row + tagbit)*nch + chunk   (tagbit 0 = pos, 1 = neg)
#define SIDE1_BASE2 (2 * SN * NCH0)            // 500000
#define NTOT2 (2 * (SN * NCH0 + EN * NCH1))    // 1020000 fine buckets

// Two-pass partition sort
#define BIN_SHIFT 11
#define NBIN2 ((NTOT2 + 2047) >> 11)  // 499 coarse bins (2048 fine buckets each)
#define T1 4096                       // edges per part1 tile
#define PG1 ((NE + T1 - 1) / T1)      // 245 tiles per adjacency
#define HB 256                        // hist blocks per adjacency

typedef float f32x4 __attribute__((ext_vector_type(4)));
typedef float f32x2 __attribute__((ext_vector_type(2)));
typedef short bf16x8 __attribute__((ext_vector_type(8)));

__device__ __forceinline__ float sigmoidf_(float v) { return 1.f / (1.f + __expf(-v)); }
__device__ __forceinline__ float bf_lo(unsigned u) { return __uint_as_float(u << 16); }
__device__ __forceinline__ float bf_hi(unsigned u) { return __uint_as_float(u & 0xffff0000u); }
__device__ __forceinline__ float bf_one(unsigned short s) { return __uint_as_float((unsigned)s << 16); }
__device__ __forceinline__ unsigned packbf2(float a, float b) {
    __hip_bfloat16 ha = __float2bfloat16(a), hb = __float2bfloat16(b);
    unsigned short ua = *(unsigned short*)&ha, ub = *(unsigned short*)&hb;
    return (unsigned)ua | ((unsigned)ub << 16);
}
__device__ __forceinline__ unsigned short packbf1(float a) {
    __hip_bfloat16 ha = __float2bfloat16(a);
    return *(unsigned short*)&ha;
}

struct CsrB {
    const int* rows[4]; const int* cols[4]; const float* vals[4];
};

__device__ __forceinline__ int bucket_idx(int a, int r, int cc) {
    int side = a >> 1;
    int nch = side ? NCH1 : NCH0;
    int base = side ? SIDE1_BASE2 : 0;
    int tb = a & 1;                    // a=0,2 pos (first); a=1,3 neg (second)
    return base + (2 * r + tb) * nch + (cc >> CH_SHIFT);
}

// ---------------------------------------------------------------------------
// Coarse histogram (499 bins), LDS-staged
// ---------------------------------------------------------------------------
__global__ __launch_bounds__(256) void hist_coarse(CsrB c, int* __restrict__ cnt) {
    __shared__ int h[512];
    const int t = threadIdx.x;
    h[t] = 0; h[t + 256] = 0;
    __syncthreads();
    const int a = blockIdx.x >> 8;
    const int tile = blockIdx.x & 255;
    const int per = (NE + HB - 1) / HB;
    const int beg = tile * per, end = min(beg + per, NE);
    for (int i = beg + t; i < end; i += 256)
        atomicAdd(&h[bucket_idx(a, c.rows[a][i], c.cols[a][i]) >> BIN_SHIFT], 1);
    __syncthreads();
    if (h[t]) atomicAdd(&cnt[t], h[t]);
    if (h[t + 256]) atomicAdd(&cnt[t + 256], h[t + 256]);
}

// 1-block exclusive scan of coarse counts -> base[NBIN2+1] and tails[NBIN2]
__global__ __launch_bounds__(512) void scan_coarse(const int* __restrict__ cnt,
                                                   int* __restrict__ base,
                                                   int* __restrict__ tails) {
    __shared__ int sh[512];
    const int t = threadIdx.x;
    const int v = (t < NBIN2) ? cnt[t] : 0;
    sh[t] = v;
    __syncthreads();
    for (int o = 1; o < 512; o <<= 1) {
        int x = sh[t]; int u = (t >= o) ? sh[t - o] : 0;
        __syncthreads(); sh[t] = x + u; __syncthreads();
    }
    if (t < NBIN2) {
        const int ex = sh[t] - v;
        base[t] = ex;
        tails[t] = ex;
    }
    if (t == 511) base[NBIN2] = sh[511];
}

// ---------------------------------------------------------------------------
// part1: multisplit edges into coarse-bin segments with coalesced writes.
// Record int2: .x = col(0..15) | fine_bucket_low11(17..27), .y = f32 val (plain)
// ---------------------------------------------------------------------------
__global__ __launch_bounds__(512) void part1(CsrB c, int* __restrict__ tails,
                                             int2* __restrict__ stg) {
    __shared__ int2 srec[T1];
    __shared__ unsigned short sbin[T1];
    __shared__ int h[512], offs[512], gbase[512], sc[512];
    const int t = threadIdx.x;
    const int a = blockIdx.x / PG1;
    const int tile = blockIdx.x - a * PG1;
    const int beg = tile * T1;
    const int cnt = min(T1, NE - beg);
    h[t] = 0;
    __syncthreads();

    int2 rec[8]; int rbin[8]; int rrank[8];
#pragma unroll
    for (int k = 0; k < 8; ++k) {
        int o = t + k * 512;
        if (o < cnt) {
            int i = beg + o;
            int cc = c.cols[a][i];
            int B = bucket_idx(a, c.rows[a][i], cc);
            int bin = B >> BIN_SHIFT;
            rec[k] = make_int2(cc | ((B & 2047) << 17), __float_as_int(c.vals[a][i]));
            rbin[k] = bin;
            rrank[k] = atomicAdd(&h[bin], 1);
        } else {
            rbin[k] = -1;
        }
    }
    __syncthreads();
    sc[t] = h[t];
    __syncthreads();
    for (int o = 1; o < 512; o <<= 1) {
        int x = sc[t]; int u = (t >= o) ? sc[t - o] : 0;
        __syncthreads(); sc[t] = x + u; __syncthreads();
    }
    offs[t] = sc[t] - h[t];
    if (h[t] > 0) gbase[t] = atomicAdd(&tails[t], h[t]);
    __syncthreads();
#pragma unroll
    for (int k = 0; k < 8; ++k) {
        if (rbin[k] >= 0) {
            int pos = offs[rbin[k]] + rrank[k];
            srec[pos] = rec[k];
            sbin[pos] = (unsigned short)rbin[k];
        }
    }
    __syncthreads();
    for (int idx = t; idx < cnt; idx += 512) {
        int b = sbin[idx];
        stg[gbase[b] + (idx - offs[b])] = srec[idx];
    }
}

// ---------------------------------------------------------------------------
// part2: one block per coarse bin. Builds fine histogram+prefix in LDS
// (producing rp_all), then scatters into the bin's own ~128KB window.
// cv record: .x = bare column, .y = f32 value
// ---------------------------------------------------------------------------
__global__ __launch_bounds__(512) void part2(const int* __restrict__ coarseBase,
                                             const int2* __restrict__ stg,
                                             int* __restrict__ rp,
                                             int2* __restrict__ cv) {
    __shared__ int cnt2[2048];
    __shared__ int tsum[512];
    const int b = blockIdx.x;
    const int t = threadIdx.x;
    const int fineBase = b << BIN_SHIFT;
    const int nf = min(2048, NTOT2 - fineBase);
    const int segBeg = coarseBase[b];
    const int segEnd = coarseBase[b + 1];
    for (int i = t; i < 2048; i += 512) cnt2[i] = 0;
    __syncthreads();
    for (int e = segBeg + t; e < segEnd; e += 512)
        atomicAdd(&cnt2[((unsigned)stg[e].x) >> 17], 1);
    __syncthreads();
    const int i4 = t * 4;
    int v0 = cnt2[i4], v1 = cnt2[i4 + 1], v2 = cnt2[i4 + 2], v3 = cnt2[i4 + 3];
    tsum[t] = v0 + v1 + v2 + v3;
    __syncthreads();
    for (int o = 1; o < 512; o <<= 1) {
        int x = tsum[t]; int u = (t >= o) ? tsum[t - o] : 0;
        __syncthreads(); tsum[t] = x + u; __syncthreads();
    }
    const int pre = (t == 0) ? 0 : tsum[t - 1];
    const int p0 = pre, p1 = pre + v0, p2 = p1 + v1, p3 = p2 + v2;
    cnt2[i4] = p0; cnt2[i4 + 1] = p1; cnt2[i4 + 2] = p2; cnt2[i4 + 3] = p3;
    if (i4 + 0 < nf) rp[fineBase + i4 + 0] = segBeg + p0;
    if (i4 + 1 < nf) rp[fineBase + i4 + 1] = segBeg + p1;
    if (i4 + 2 < nf) rp[fineBase + i4 + 2] = segBeg + p2;
    if (i4 + 3 < nf) rp[fineBase + i4 + 3] = segBeg + p3;
    if (b == NBIN2 - 1 && t == 511) rp[NTOT2] = segEnd;
    __syncthreads();
    for (int e = segBeg + t; e < segEnd; e += 512) {
        int2 r = stg[e];
        int pos = segBeg + atomicAdd(&cnt2[((unsigned)r.x) >> 17], 1);
        cv[pos] = make_int2(r.x & 0xFFFF, r.y);
    }
}

// ---------------------------------------------------------------------------
// fp32 -> bf16 conversion (small weight tables only)
// ---------------------------------------------------------------------------
__global__ __launch_bounds__(256) void f2bf(const float* __restrict__ src,
                                            unsigned short* __restrict__ dst, int n2) {
    int i = blockIdx.x * 256 + threadIdx.x;
    if (i < n2) {
        float2 f = ((const float2*)src)[i];
        ((unsigned*)dst)[i] = packbf2(f.x, f.y);
    }
}

// ---------------------------------------------------------------------------
// bf16 -> fp8 e4m3 shadow conversion (4 elems/thread)
// ---------------------------------------------------------------------------
__global__ __launch_bounds__(256) void bf2fp8(const unsigned* __restrict__ src,
                                              unsigned* __restrict__ dst, int n4) {
    int i = blockIdx.x * 256 + threadIdx.x;
    if (i < n4) {
        unsigned a = src[2 * i], b = src[2 * i + 1];
        float f0 = bf_lo(a), f1 = bf_hi(a), f2 = bf_lo(b), f3 = bf_hi(b);
        int pk = __builtin_amdgcn_cvt_pk_fp8_f32(f0, f1, 0, false);
        pk = __builtin_amdgcn_cvt_pk_fp8_f32(f2, f3, pk, true);
        dst[i] = (unsigned)pk;
    }
}

// ---------------------------------------------------------------------------
// Projection MFMA GEMM: out[M,128](bf16) = X[M,KK](f32) @ W[128,KK]^T(bf16)
// ---------------------------------------------------------------------------
template <int KK>
__global__ __launch_bounds__(256) void gemm_proj(const float* __restrict__ X,
                                                 const unsigned short* __restrict__ W,
                                                 unsigned short* __restrict__ out, int M) {
    constexpr int PITCH = KK + 8;
    __shared__ unsigned short Wl[128 * PITCH];
    const int t = threadIdx.x;
    for (int idx = t * 8; idx < 128 * KK; idx += 2048) {
        int r = idx / KK, k = idx - r * KK;
        *(uint4*)(&Wl[r * PITCH + k]) = *(const uint4*)(&W[idx]);
    }
    __syncthreads();
    const int lane = t & 63;
    const int nm = lane & 15;
    const int quad = lane >> 4;
    const int row0 = blockIdx.x * 64 + (t >> 6) * 16;
    if (row0 >= M) return;

    f32x4 acc[8];
#pragma unroll
    for (int nt = 0; nt < 8; ++nt) acc[nt] = (f32x4){0.f, 0.f, 0.f, 0.f};

    const float* xrow = X + (size_t)(row0 + nm) * KK + quad * 8;
#pragma unroll
    for (int ks = 0; ks < KK / 32; ++ks) {
        float4 f0 = *(const float4*)(xrow + ks * 32);
        float4 f1 = *(const float4*)(xrow + ks * 32 + 4);
        unsigned q[4] = {packbf2(f0.x, f0.y), packbf2(f0.z, f0.w),
                         packbf2(f1.x, f1.y), packbf2(f1.z, f1.w)};
        bf16x8 a = *(bf16x8*)q;
#pragma unroll
        for (int nt = 0; nt < 8; ++nt) {
            bf16x8 b = *(const bf16x8*)(&Wl[(nt * 16 + nm) * PITCH + ks * 32 + quad * 8]);
            acc[nt] = __builtin_amdgcn_mfma_f32_16x16x32_bf16(a, b, acc[nt], 0, 0, 0);
        }
    }
    unsigned short* orow = out + (size_t)(row0 + quad * 4) * 128 + nm;
#pragma unroll
    for (int r = 0; r < 4; ++r)
#pragma unroll
        for (int nt = 0; nt < 8; ++nt)
            orow[(size_t)r * 128 + nt * 16] = packbf1(acc[nt][r]);
}

// ---------------------------------------------------------------------------
// Fused dual-weight MFMA GEMM, BOTH sides in one dispatch (in-place safe):
//   out = (agg1 + d1.*y)@W1^T + (agg0 + d0.*y)@W0^T + (b1+b0)
// ---------------------------------------------------------------------------
__global__ __launch_bounds__(256) void gemm2_mfma(
    const unsigned short* __restrict__ agg1S, const unsigned short* __restrict__ agg0S,
    const unsigned short* __restrict__ yS,
    const float* __restrict__ d1S, const float* __restrict__ d0S,
    unsigned short* __restrict__ outS,
    const unsigned short* __restrict__ agg1E, const unsigned short* __restrict__ agg0E,
    const unsigned short* __restrict__ yE,
    const float* __restrict__ d1E, const float* __restrict__ d0E,
    unsigned short* __restrict__ outE,
    const unsigned short* __restrict__ W1, const unsigned short* __restrict__ W0,
    const float* __restrict__ b1, const float* __restrict__ b0, int nblkS) {
    constexpr int PITCH = 136;
    __shared__ unsigned short Wl[2 * 128 * PITCH];
    const int t = threadIdx.x;
    for (int idx = t * 8; idx < 128 * 128; idx += 2048) {
        int r = idx >> 7, k = idx & 127;
        *(uint4*)(&Wl[r * PITCH + k]) = *(const uint4*)(&W1[idx]);
        *(uint4*)(&Wl[128 * PITCH + r * PITCH + k]) = *(const uint4*)(&W0[idx]);
    }
    __syncthreads();
    const bool sideE = (int)blockIdx.x >= nblkS;
    const unsigned short* agg1 = sideE ? agg1E : agg1S;
    const unsigned short* agg0 = sideE ? agg0E : agg0S;
    const unsigned short* y    = sideE ? yE : yS;
    const float* d1 = sideE ? d1E : d1S;
    const float* d0 = sideE ? d0E : d0S;
    unsigned short* out = sideE ? outE : outS;
    const int M = sideE ? EN : SN;
    const int lane = t & 63;
    const int nm = lane & 15;
    const int quad = lane >> 4;
    const int row0 = ((int)blockIdx.x - (sideE ? nblkS : 0)) * 64 + (t >> 6) * 16;
    if (row0 >= M) return;

    const float d1v = d1[row0 + nm];
    const float d0v = d0[row0 + nm];

    f32x4 acc[8];
#pragma unroll
    for (int nt = 0; nt < 8; ++nt) acc[nt] = (f32x4){0.f, 0.f, 0.f, 0.f};

    const size_t rbase = (size_t)(row0 + nm) * 128 + quad * 8;
#pragma unroll
    for (int ks = 0; ks < 4; ++ks) {
        uint4 ua1 = *(const uint4*)(agg1 + rbase + ks * 32);
        uint4 ua0 = *(const uint4*)(agg0 + rbase + ks * 32);
        uint4 uy  = *(const uint4*)(y    + rbase + ks * 32);
        uint4 p1, p0;
        {
            unsigned* a1 = (unsigned*)&ua1; unsigned* a0 = (unsigned*)&ua0;
            unsigned* yy = (unsigned*)&uy;
            unsigned* q1 = (unsigned*)&p1; unsigned* q0 = (unsigned*)&p0;
#pragma unroll
            for (int w = 0; w < 4; ++w) {
                float ylo = bf_lo(yy[w]), yhi = bf_hi(yy[w]);
                q1[w] = packbf2(bf_lo(a1[w]) + d1v * ylo, bf_hi(a1[w]) + d1v * yhi);
                q0[w] = packbf2(bf_lo(a0[w]) + d0v * ylo, bf_hi(a0[w]) + d0v * yhi);
            }
        }
        bf16x8 af1 = *(bf16x8*)&p1;
        bf16x8 af0 = *(bf16x8*)&p0;
#pragma unroll
        for (int nt = 0; nt < 8; ++nt) {
            bf16x8 bw1 = *(const bf16x8*)(&Wl[(nt * 16 + nm) * PITCH + ks * 32 + quad * 8]);
            acc[nt] = __builtin_amdgcn_mfma_f32_16x16x32_bf16(af1, bw1, acc[nt], 0, 0, 0);
            bf16x8 bw0 = *(const bf16x8*)(&Wl[128 * PITCH + (nt * 16 + nm) * PITCH + ks * 32 + quad * 8]);
            acc[nt] = __builtin_amdgcn_mfma_f32_16x16x32_bf16(af0, bw0, acc[nt], 0, 0, 0);
        }
    }
    unsigned short* orow = out + (size_t)(row0 + quad * 4) * 128 + nm;
#pragma unroll
    for (int nt = 0; nt < 8; ++nt) {
        float bb = b1[nt * 16 + nm] + b0[nt * 16 + nm];
#pragma unroll
        for (int r = 0; r < 4; ++r)
            orow[(size_t)r * 128 + nt * 16] = packbf1(acc[nt][r] + bb);
    }
}

// ---------------------------------------------------------------------------
// Pair-SPMM: 2 edges per wave instruction. Half-wave h handles edge e+h;
// lane c (0..31) covers cols 4c..4c+3 via one u32 fp8 gather. Tag-phase
// separated by the sort (pos edges then neg edges per row). Cross-half
// reduction via shfl_xor(32); half 0 writes pos row, half 1 neg row.
// ---------------------------------------------------------------------------
__global__ __launch_bounds__(256) void spmm_all(
    const int* __restrict__ rp, const long long* __restrict__ cv,
    const unsigned char* __restrict__ kd8, const unsigned char* __restrict__ st8,
    unsigned short* __restrict__ as1, unsigned short* __restrict__ as0,
    unsigned short* __restrict__ ae1, unsigned short* __restrict__ ae0) {
    const int wave = (blockIdx.x * 256 + threadIdx.x) >> 6;
    const int lane = threadIdx.x & 63;
    if (wave >= SN + EN) return;
    const bool sideE = wave >= SN;
    const int r = sideE ? wave - SN : wave;
    const int nch = sideE ? NCH1 : NCH0;
    const int* rpb = rp + (sideE ? SIDE1_BASE2 : 0);
    const int half = lane >> 5;
    const int c = lane & 31;
    const unsigned char* g8 = (sideE ? st8 : kd8) + c * 4;

    const int rbase = 2 * r * nch;
    const int e0 = rpb[rbase];
    const int em = rpb[rbase + nch];
    const int ee = rpb[rbase + 2 * nch];

    float accP[4] = {0.f, 0.f, 0.f, 0.f};
    float accN[4] = {0.f, 0.f, 0.f, 0.f};

#define PAIR(E, ACC)                                                        \
    {                                                                       \
        int col = (int)((E) & 0xFFFF);                                      \
        float v = __int_as_float((int)((E) >> 32));                         \
        unsigned u = *(const unsigned*)(g8 + (col << 7));                   \
        f32x2 gA = __builtin_amdgcn_cvt_pk_f32_fp8((int)u, false);          \
        f32x2 gB = __builtin_amdgcn_cvt_pk_f32_fp8((int)u, true);           \
        ACC[0] += v * gA.x; ACC[1] += v * gA.y;                             \
        ACC[2] += v * gB.x; ACC[3] += v * gB.y;                             \
    }

    // phase 1: pos edges [e0, em)
    {
        int e = e0;
        for (; e + 8 <= em; e += 8) {
            long long E0 = cv[e + half];
            long long E1 = cv[e + 2 + half];
            long long E2 = cv[e + 4 + half];
            long long E3 = cv[e + 6 + half];
            PAIR(E0, accP) PAIR(E1, accP) PAIR(E2, accP) PAIR(E3, accP)
        }
        for (; e + 2 <= em; e += 2) {
            long long E0 = cv[e + half];
            PAIR(E0, accP)
        }
        if (e < em) {
            long long E0 = cv[e];
            if (half) E0 &= 0xFFFFFFFFLL;   // zero the value for half 1
            PAIR(E0, accP)
        }
    }
    // phase 2: neg edges [em, ee)
    {
        int e = em;
        for (; e + 8 <= ee; e += 8) {
            long long E0 = cv[e + half];
            long long E1 = cv[e + 2 + half];
            long long E2 = cv[e + 4 + half];
            long long E3 = cv[e + 6 + half];
            PAIR(E0, accN) PAIR(E1, accN) PAIR(E2, accN) PAIR(E3, accN)
        }
        for (; e + 2 <= ee; e += 2) {
            long long E0 = cv[e + half];
            PAIR(E0, accN)
        }
        if (e < ee) {
            long long E0 = cv[e];
            if (half) E0 &= 0xFFFFFFFFLL;
            PAIR(E0, accN)
        }
    }
#undef PAIR

#pragma unroll
    for (int j = 0; j < 4; ++j) {
        accP[j] += __shfl_xor(accP[j], 32);
        accN[j] += __shfl_xor(accN[j], 32);
    }
    unsigned short* o1 = sideE ? ae1 : as1;
    unsigned short* o0 = sideE ? ae0 : as0;
    const int base = (r << 7) + c * 4;
    if (half == 0) {
        *(uint2*)&o1[base] = make_uint2(packbf2(accP[0], accP[1]),
                                        packbf2(accP[2], accP[3]));
    } else {
        *(uint2*)&o0[base] = make_uint2(packbf2(accN[0], accN[1]),
                                        packbf2(accN[2], accN[3]));
    }
}

// ---------------------------------------------------------------------------
// fp32 tiled GEMM for the head: out = act( X @ |W|^T + b )
// ---------------------------------------------------------------------------
template <int KK, int NCOLS, int ROWS, bool ABSW, bool SIG>
__global__ __launch_bounds__(256) void gemm_xwT(const float* __restrict__ X,
                                                const float* __restrict__ W,
                                                const float* __restrict__ bias,
                                                float* __restrict__ out, int M) {
    constexpr int KP = 32;
    constexpr int NG = 256 / NCOLS;
    constexpr int RT = ROWS / NG;
    __shared__ float BT[KP * (NCOLS + 1)];
    __shared__ float Xl[ROWS * (KK + 1)];
    const int t = threadIdx.x;
    const int j = t % NCOLS;
    const int rg = t / NCOLS;
    const int row0 = blockIdx.x * ROWS;

    for (int idx = t; idx < ROWS * KK; idx += 256) {
        int r = idx / KK, k = idx % KK;
        int gr = row0 + r;
        Xl[r * (KK + 1) + k] = (gr < M) ? X[gr * KK + k] : 0.f;
    }
    float acc[RT];
#pragma unroll
    for (int i = 0; i < RT; ++i) acc[i] = 0.f;

    for (int k0 = 0; k0 < KK; k0 += KP) {
        __syncthreads();
        for (int idx = t; idx < NCOLS * KP; idx += 256) {
            int jj = idx / KP, kp = idx % KP;
            float w = W[jj * KK + k0 + kp];
            BT[kp * (NCOLS + 1) + jj] = ABSW ? fabsf(w) : w;
        }
        __syncthreads();
#pragma unroll
        for (int kp = 0; kp < KP; ++kp) {
            float b = BT[kp * (NCOLS + 1) + j];
#pragma unroll
            for (int rr = 0; rr < RT; ++rr)
                acc[rr] += Xl[(rg * RT + rr) * (KK + 1) + k0 + kp] * b;
        }
    }
    float bj = bias ? bias[j] : 0.f;
#pragma unroll
    for (int rr = 0; rr < RT; ++rr) {
        int gr = row0 + rg * RT + rr;
        if (gr < M) {
            float v = acc[rr] + bj;
            out[gr * NCOLS + j] = SIG ? sigmoidf_(v) : v;
        }
    }
}

// ---------------------------------------------------------------------------
// Head kernels
// ---------------------------------------------------------------------------
__global__ __launch_bounds__(128) void head1_kernel(
    const int* __restrict__ stu_id, const int* __restrict__ exer_id,
    const float* __restrict__ kn_emb, const unsigned short* __restrict__ stat,
    const unsigned short* __restrict__ kdiff, const float* __restrict__ stu_bias,
    const float* __restrict__ e_disc, float* __restrict__ x) {
    const int b = blockIdx.x;
    const int k = threadIdx.x;
    const int sid = stu_id[b], eid = exer_id[b];
    float disc = sigmoidf_(e_disc[eid]);
    float sb = sigmoidf_(bf_one(stat[(sid << 7) + k]) + stu_bias[sid]);
    float kd = sigmoidf_(bf_one(kdiff[(eid << 7) + k]));
    x[(b << 7) + k] = disc * (sb - kd) * kn_emb[(b << 7) + k];
}

__global__ __launch_bounds__(256) void pn3_kernel(const float* __restrict__ h2,
                                                  const float* __restrict__ w3,
                                                  const float* __restrict__ b3,
                                                  float* __restrict__ out) {
    __shared__ float wl[128];
    const int t = threadIdx.x;
    if (t < 128) wl[t] = fabsf(w3[t]);
    __syncthreads();
    const int b = blockIdx.x * 256 + t;
    float acc = 0.f;
#pragma unroll 4
    for (int k = 0; k < 128; ++k) acc += h2[(b << 7) + k] * wl[k];
    out[b] = sigmoidf_(acc + b3[0]);
}

// ---------------------------------------------------------------------------
// Launch
// ---------------------------------------------------------------------------
static inline size_t align256(size_t x) { return (x + 255) & ~size_t(255); }

extern "C" void kernel_launch(void* const* d_in, const int* in_sizes, int n_in,
                              void* d_out, int out_size, void* d_ws, size_t ws_size,
                              hipStream_t stream) {
    const int*   stu_id   = (const int*)d_in[0];
    const int*   exer_id  = (const int*)d_in[1];
    const float* kn_emb   = (const float*)d_in[2];
    const float* stu_emb  = (const float*)d_in[3];
    const float* exer_emb = (const float*)d_in[4];
    const float* kn_base  = (const float*)d_in[5];
    const float* stu_bias = (const float*)d_in[6];
    const float* e_disc   = (const float*)d_in[7];
    const float* W1_w     = (const float*)d_in[8];
    const float* W1_b     = (const float*)d_in[9];
    const float* W0_w     = (const float*)d_in[10];
    const float* W0_b     = (const float*)d_in[11];
    const float* pn1_w    = (const float*)d_in[12];
    const float* pn1_b    = (const float*)d_in[13];
    const float* pn2_w    = (const float*)d_in[14];
    const float* pn2_b    = (const float*)d_in[15];
    const float* pn3_w    = (const float*)d_in[16];
    const float* pn3_b    = (const float*)d_in[17];
    const int*   ui1_r = (const int*)d_in[18]; const int* ui1_c = (const int*)d_in[19];
    const float* ui1_v = (const float*)d_in[20];
    const int*   iu1_r = (const int*)d_in[21]; const int* iu1_c = (const int*)d_in[22];
    const float* iu1_v = (const float*)d_in[23];
    const int*   ui0_r = (const int*)d_in[24]; const int* ui0_c = (const int*)d_in[25];
    const float* ui0_v = (const float*)d_in[26];
    const int*   iu0_r = (const int*)d_in[27]; const int* iu0_c = (const int*)d_in[28];
    const float* iu0_v = (const float*)d_in[29];
    const float* d_i_1 = (const float*)d_in[30];
    const float* d_j_1 = (const float*)d_in[31];
    const float* d_i_0 = (const float*)d_in[32];
    const float* d_j_0 = (const float*)d_in[33];
    float* out = (float*)d_out;

    typedef unsigned short u16;
    typedef unsigned char u8;
    char* p = (char*)d_ws;
    size_t off = 0;
    auto alloc = [&](size_t bytes) { char* q = p + off; off += align256(bytes); return q; };
    // bf16 state — stat & kdiff contiguous (bf2fp8 spans both)
    u16* stat  = (u16*)alloc(size_t(SN) * KN * 2);
    u16* kdiff = (u16*)alloc(size_t(EN) * KN * 2);
    // fp8 shadows — contiguous pair
    u8* st8 = (u8*)alloc(size_t(SN) * KN);
    u8* kd8 = (u8*)alloc(size_t(EN) * KN);
    // aggregation buffers
    u16* as1 = (u16*)alloc(size_t(SN) * KN * 2);
    u16* as0 = (u16*)alloc(size_t(SN) * KN * 2);
    u16* ae1 = (u16*)alloc(size_t(EN) * KN * 2);
    u16* ae0 = (u16*)alloc(size_t(EN) * KN * 2);
    // bf16 weight tables
    u16* Kb  = (u16*)alloc(size_t(KN) * DN * 2);
    u16* Wb1 = (u16*)alloc(size_t(KN) * KN * 2);
    u16* Wb0 = (u16*)alloc(size_t(KN) * KN * 2);
    // sort structures
    int*  coarseCnt  = (int*)alloc(512 * 4);
    int*  coarseBase = (int*)alloc((NBIN2 + 1) * 4);
    int*  tails      = (int*)alloc(512 * 4);
    int*  rp_all     = (int*)alloc(size_t(NTOT2 + 1) * 4);
    int2* stg        = (int2*)alloc(size_t(4) * NE * 8);
    int2* cv_all     = (int2*)alloc(size_t(4) * NE * 8);
    // head
    float* xh = (float*)alloc(size_t(BN) * KN * 4);
    float* h1 = (float*)alloc(size_t(BN) * 256 * 4);
    float* h2 = (float*)alloc(size_t(BN) * 128 * 4);
    if (off > ws_size) return;

    CsrB c;
    c.rows[0] = ui1_r; c.cols[0] = ui1_c; c.vals[0] = ui1_v;
    c.rows[1] = ui0_r; c.cols[1] = ui0_c; c.vals[1] = ui0_v;
    c.rows[2] = iu1_r; c.cols[2] = iu1_c; c.vals[2] = iu1_v;
    c.rows[3] = iu0_r; c.cols[3] = iu0_c; c.vals[3] = iu0_v;

    // ---- two-pass partition sort (key = row, tag, chunk) ----
    hipMemsetAsync(coarseCnt, 0, 512 * 4, stream);
    hist_coarse<<<4 * HB, 256, 0, stream>>>(c, coarseCnt);
    scan_coarse<<<1, 512, 0, stream>>>(coarseCnt, coarseBase, tails);
    part1<<<4 * PG1, 512, 0, stream>>>(c, tails, stg);
    part2<<<NBIN2, 512, 0, stream>>>(coarseBase, stg, rp_all, cv_all);

    // ---- bf16 weight conversions ----
    f2bf<<<(KN * DN / 2 + 255) / 256, 256, 0, stream>>>(kn_base, Kb, KN * DN / 2);
    f2bf<<<(KN * KN / 2 + 255) / 256, 256, 0, stream>>>(W1_w, Wb1, KN * KN / 2);
    f2bf<<<(KN * KN / 2 + 255) / 256, 256, 0, stream>>>(W0_w, Wb0, KN * KN / 2);

    // ---- projections (read f32 embeddings directly) ----
    gemm_proj<DN><<<(SN + 63) / 64, 256, 0, stream>>>(stu_emb, Kb, stat, SN);
    gemm_proj<DN><<<(EN + 63) / 64, 256, 0, stream>>>(exer_emb, Kb, kdiff, EN);

    const int N4 = (SN + EN) * KN / 4;   // fp8-shadow conversion span (both tables)
    const int nblkS = (SN + 63) / 64, nblkE = (EN + 63) / 64;

    // ---- GCN layers ----
    for (int l = 0; l < NLAYER; ++l) {
        bf2fp8<<<(N4 + 255) / 256, 256, 0, stream>>>((const unsigned*)stat,
                                                     (unsigned*)st8, N4);
        spmm_all<<<(SN + EN + 3) / 4, 256, 0, stream>>>(
            rp_all, (const long long*)cv_all, kd8, st8, as1, as0, ae1, ae0);
        gemm2_mfma<<<nblkS + nblkE, 256, 0, stream>>>(
            as1, as0, stat, d_i_1, d_i_0, stat,
            ae1, ae0, kdiff, d_j_1, d_j_0, kdiff,
            Wb1, Wb0, W1_b, W0_b, nblkS);
    }

    // ---- head ----
    head1_kernel<<<BN, 128, 0, stream>>>(stu_id, exer_id, kn_emb, stat, kdiff,
                                         stu_bias, e_disc, xh);
    gemm_xwT<128, 256, 16, true, true><<<BN / 16, 256, 0, stream>>>(xh, pn1_w, pn1_b, h1, BN);
    gemm_xwT<256, 128, 32, true, true><<<BN / 32, 256, 0, stream>>>(h1, pn2_w, pn2_b, h2, BN);
    pn3_kernel<<<BN / 256, 256, 0, stream>>>(h2, pn3_w, pn3_b, out);
    (void)out_size; (void)n_in; (void)in_sizes;
}

// Round 10
// 688.583 us; speedup vs baseline: 1.2573x; 1.0694x over previous
//
#include <hip/hip_runtime.h>
#include <hip/hip_bf16.h>

// Problem constants (from reference)
#define SN 50000
#define EN 20000
#define KN 128
#define DN 64
#define BN 4096
#define NE 1000000
#define NLAYER 3

// Column-chunk bucketing: chunk = 4096 gather-table rows (fp8: 0.5MB)
#define CH_SHIFT 12
#define NCH0 5                        // side0 (ui): cols index kdiff, EN -> 5 chunks
#define NCH1 13                       // side1 (iu): cols index stat,  SN -> 13 chunks
// fine bucket = (2*row + tagbit)*nch + chunk   (tagbit 0 = pos, 1 = neg)
#define SIDE1_BASE2 (2 * SN * NCH0)            // 500000
#define NTOT2 (2 * (SN * NCH0 + EN * NCH1))    // 1020000 fine buckets

// Two-pass partition sort
#define BIN_SHIFT 11
#define NBIN2 ((NTOT2 + 2047) >> 11)  // 499 coarse bins (2048 fine buckets each)
#define T1 4096                       // edges per part1 tile
#define PG1 ((NE + T1 - 1) / T1)      // 245 tiles per adjacency
#define HB 256                        // hist blocks per adjacency

typedef float f32x4 __attribute__((ext_vector_type(4)));
typedef float f32x2 __attribute__((ext_vector_type(2)));
typedef short bf16x8 __attribute__((ext_vector_type(8)));

__device__ __forceinline__ float sigmoidf_(float v) { return 1.f / (1.f + __expf(-v)); }
__device__ __forceinline__ float bf_lo(unsigned u) { return __uint_as_float(u << 16); }
__device__ __forceinline__ float bf_hi(unsigned u) { return __uint_as_float(u & 0xffff0000u); }
__device__ __forceinline__ float bf_one(unsigned short s) { return __uint_as_float((unsigned)s << 16); }
__device__ __forceinline__ unsigned packbf2(float a, float b) {
    __hip_bfloat16 ha = __float2bfloat16(a), hb = __float2bfloat16(b);
    unsigned short ua = *(unsigned short*)&ha, ub = *(unsigned short*)&hb;
    return (unsigned)ua | ((unsigned)ub << 16);
}
__device__ __forceinline__ unsigned short packbf1(float a) {
    __hip_bfloat16 ha = __float2bfloat16(a);
    return *(unsigned short*)&ha;
}

struct CsrB {
    const int* rows[4]; const int* cols[4]; const float* vals[4];
};

__device__ __forceinline__ int bucket_idx(int a, int r, int cc) {
    int side = a >> 1;
    int nch = side ? NCH1 : NCH0;
    int base = side ? SIDE1_BASE2 : 0;
    int tb = a & 1;                    // a=0,2 pos (first); a=1,3 neg (second)
    return base + (2 * r + tb) * nch + (cc >> CH_SHIFT);
}

// ---------------------------------------------------------------------------
// Coarse histogram (499 bins), LDS-staged
// ---------------------------------------------------------------------------
__global__ __launch_bounds__(256) void hist_coarse(CsrB c, int* __restrict__ cnt) {
    __shared__ int h[512];
    const int t = threadIdx.x;
    h[t] = 0; h[t + 256] = 0;
    __syncthreads();
    const int a = blockIdx.x >> 8;
    const int tile = blockIdx.x & 255;
    const int per = (NE + HB - 1) / HB;
    const int beg = tile * per, end = min(beg + per, NE);
    for (int i = beg + t; i < end; i += 256)
        atomicAdd(&h[bucket_idx(a, c.rows[a][i], c.cols[a][i]) >> BIN_SHIFT], 1);
    __syncthreads();
    if (h[t]) atomicAdd(&cnt[t], h[t]);
    if (h[t + 256]) atomicAdd(&cnt[t + 256], h[t + 256]);
}

// 1-block exclusive scan of coarse counts -> base[NBIN2+1] and tails[NBIN2]
__global__ __launch_bounds__(512) void scan_coarse(const int* __restrict__ cnt,
                                                   int* __restrict__ base,
                                                   int* __restrict__ tails) {
    __shared__ int sh[512];
    const int t = threadIdx.x;
    const int v = (t < NBIN2) ? cnt[t] : 0;
    sh[t] = v;
    __syncthreads();
    for (int o = 1; o < 512; o <<= 1) {
        int x = sh[t]; int u = (t >= o) ? sh[t - o] : 0;
        __syncthreads(); sh[t] = x + u; __syncthreads();
    }
    if (t < NBIN2) {
        const int ex = sh[t] - v;
        base[t] = ex;
        tails[t] = ex;
    }
    if (t == 511) base[NBIN2] = sh[511];
}

// ---------------------------------------------------------------------------
// part1: multisplit edges into coarse-bin segments with coalesced writes.
// Record int2: .x = col(0..15) | fine_bucket_low11(17..27), .y = f32 val (plain)
// ---------------------------------------------------------------------------
__global__ __launch_bounds__(512) void part1(CsrB c, int* __restrict__ tails,
                                             int2* __restrict__ stg) {
    __shared__ int2 srec[T1];
    __shared__ unsigned short sbin[T1];
    __shared__ int h[512], offs[512], gbase[512], sc[512];
    const int t = threadIdx.x;
    const int a = blockIdx.x / PG1;
    const int tile = blockIdx.x - a * PG1;
    const int beg = tile * T1;
    const int cnt = min(T1, NE - beg);
    h[t] = 0;
    __syncthreads();

    int2 rec[8]; int rbin[8]; int rrank[8];
#pragma unroll
    for (int k = 0; k < 8; ++k) {
        int o = t + k * 512;
        if (o < cnt) {
            int i = beg + o;
            int cc = c.cols[a][i];
            int B = bucket_idx(a, c.rows[a][i], cc);
            int bin = B >> BIN_SHIFT;
            rec[k] = make_int2(cc | ((B & 2047) << 17), __float_as_int(c.vals[a][i]));
            rbin[k] = bin;
            rrank[k] = atomicAdd(&h[bin], 1);
        } else {
            rbin[k] = -1;
        }
    }
    __syncthreads();
    sc[t] = h[t];
    __syncthreads();
    for (int o = 1; o < 512; o <<= 1) {
        int x = sc[t]; int u = (t >= o) ? sc[t - o] : 0;
        __syncthreads(); sc[t] = x + u; __syncthreads();
    }
    offs[t] = sc[t] - h[t];
    if (h[t] > 0) gbase[t] = atomicAdd(&tails[t], h[t]);
    __syncthreads();
#pragma unroll
    for (int k = 0; k < 8; ++k) {
        if (rbin[k] >= 0) {
            int pos = offs[rbin[k]] + rrank[k];
            srec[pos] = rec[k];
            sbin[pos] = (unsigned short)rbin[k];
        }
    }
    __syncthreads();
    for (int idx = t; idx < cnt; idx += 512) {
        int b = sbin[idx];
        stg[gbase[b] + (idx - offs[b])] = srec[idx];
    }
}

// ---------------------------------------------------------------------------
// part2: one block per coarse bin. Builds fine histogram+prefix in LDS
// (producing rp_all), then scatters into the bin's own ~128KB window.
// cv record: .x = bare column, .y = f32 value
// ---------------------------------------------------------------------------
__global__ __launch_bounds__(512) void part2(const int* __restrict__ coarseBase,
                                             const int2* __restrict__ stg,
                                             int* __restrict__ rp,
                                             int2* __restrict__ cv) {
    __shared__ int cnt2[2048];
    __shared__ int tsum[512];
    const int b = blockIdx.x;
    const int t = threadIdx.x;
    const int fineBase = b << BIN_SHIFT;
    const int nf = min(2048, NTOT2 - fineBase);
    const int segBeg = coarseBase[b];
    const int segEnd = coarseBase[b + 1];
    for (int i = t; i < 2048; i += 512) cnt2[i] = 0;
    __syncthreads();
    for (int e = segBeg + t; e < segEnd; e += 512)
        atomicAdd(&cnt2[((unsigned)stg[e].x) >> 17], 1);
    __syncthreads();
    const int i4 = t * 4;
    int v0 = cnt2[i4], v1 = cnt2[i4 + 1], v2 = cnt2[i4 + 2], v3 = cnt2[i4 + 3];
    tsum[t] = v0 + v1 + v2 + v3;
    __syncthreads();
    for (int o = 1; o < 512; o <<= 1) {
        int x = tsum[t]; int u = (t >= o) ? tsum[t - o] : 0;
        __syncthreads(); tsum[t] = x + u; __syncthreads();
    }
    const int pre = (t == 0) ? 0 : tsum[t - 1];
    const int p0 = pre, p1 = pre + v0, p2 = p1 + v1, p3 = p2 + v2;
    cnt2[i4] = p0; cnt2[i4 + 1] = p1; cnt2[i4 + 2] = p2; cnt2[i4 + 3] = p3;
    if (i4 + 0 < nf) rp[fineBase + i4 + 0] = segBeg + p0;
    if (i4 + 1 < nf) rp[fineBase + i4 + 1] = segBeg + p1;
    if (i4 + 2 < nf) rp[fineBase + i4 + 2] = segBeg + p2;
    if (i4 + 3 < nf) rp[fineBase + i4 + 3] = segBeg + p3;
    if (b == NBIN2 - 1 && t == 511) rp[NTOT2] = segEnd;
    __syncthreads();
    for (int e = segBeg + t; e < segEnd; e += 512) {
        int2 r = stg[e];
        int pos = segBeg + atomicAdd(&cnt2[((unsigned)r.x) >> 17], 1);
        cv[pos] = make_int2(r.x & 0xFFFF, r.y);
    }
}

// ---------------------------------------------------------------------------
// fp32 -> bf16 conversion (small weight tables only)
// ---------------------------------------------------------------------------
__global__ __launch_bounds__(256) void f2bf(const float* __restrict__ src,
                                            unsigned short* __restrict__ dst, int n2) {
    int i = blockIdx.x * 256 + threadIdx.x;
    if (i < n2) {
        float2 f = ((const float2*)src)[i];
        ((unsigned*)dst)[i] = packbf2(f.x, f.y);
    }
}

// ---------------------------------------------------------------------------
// bf16 -> fp8 e4m3 shadow conversion (4 elems/thread)
// ---------------------------------------------------------------------------
__global__ __launch_bounds__(256) void bf2fp8(const unsigned* __restrict__ src,
                                              unsigned* __restrict__ dst, int n4) {
    int i = blockIdx.x * 256 + threadIdx.x;
    if (i < n4) {
        unsigned a = src[2 * i], b = src[2 * i + 1];
        float f0 = bf_lo(a), f1 = bf_hi(a), f2 = bf_lo(b), f3 = bf_hi(b);
        int pk = __builtin_amdgcn_cvt_pk_fp8_f32(f0, f1, 0, false);
        pk = __builtin_amdgcn_cvt_pk_fp8_f32(f2, f3, pk, true);
        dst[i] = (unsigned)pk;
    }
}

// ---------------------------------------------------------------------------
// Projection MFMA GEMM: out[M,128](bf16) = X[M,KK](f32) @ W[128,KK]^T(bf16)
// ---------------------------------------------------------------------------
template <int KK>
__global__ __launch_bounds__(256) void gemm_proj(const float* __restrict__ X,
                                                 const unsigned short* __restrict__ W,
                                                 unsigned short* __restrict__ out, int M) {
    constexpr int PITCH = KK + 8;
    __shared__ unsigned short Wl[128 * PITCH];
    const int t = threadIdx.x;
    for (int idx = t * 8; idx < 128 * KK; idx += 2048) {
        int r = idx / KK, k = idx - r * KK;
        *(uint4*)(&Wl[r * PITCH + k]) = *(const uint4*)(&W[idx]);
    }
    __syncthreads();
    const int lane = t & 63;
    const int nm = lane & 15;
    const int quad = lane >> 4;
    const int row0 = blockIdx.x * 64 + (t >> 6) * 16;
    if (row0 >= M) return;

    f32x4 acc[8];
#pragma unroll
    for (int nt = 0; nt < 8; ++nt) acc[nt] = (f32x4){0.f, 0.f, 0.f, 0.f};

    const float* xrow = X + (size_t)(row0 + nm) * KK + quad * 8;
#pragma unroll
    for (int ks = 0; ks < KK / 32; ++ks) {
        float4 f0 = *(const float4*)(xrow + ks * 32);
        float4 f1 = *(const float4*)(xrow + ks * 32 + 4);
        unsigned q[4] = {packbf2(f0.x, f0.y), packbf2(f0.z, f0.w),
                         packbf2(f1.x, f1.y), packbf2(f1.z, f1.w)};
        bf16x8 a = *(bf16x8*)q;
#pragma unroll
        for (int nt = 0; nt < 8; ++nt) {
            bf16x8 b = *(const bf16x8*)(&Wl[(nt * 16 + nm) * PITCH + ks * 32 + quad * 8]);
            acc[nt] = __builtin_amdgcn_mfma_f32_16x16x32_bf16(a, b, acc[nt], 0, 0, 0);
        }
    }
    unsigned short* orow = out + (size_t)(row0 + quad * 4) * 128 + nm;
#pragma unroll
    for (int r = 0; r < 4; ++r)
#pragma unroll
        for (int nt = 0; nt < 8; ++nt)
            orow[(size_t)r * 128 + nt * 16] = packbf1(acc[nt][r]);
}

// ---------------------------------------------------------------------------
// Fused dual-weight MFMA GEMM, BOTH sides in one dispatch (in-place safe):
//   out = (agg1 + d1.*y)@W1^T + (agg0 + d0.*y)@W0^T + (b1+b0)
// ---------------------------------------------------------------------------
__global__ __launch_bounds__(256) void gemm2_mfma(
    const unsigned short* __restrict__ agg1S, const unsigned short* __restrict__ agg0S,
    const unsigned short* __restrict__ yS,
    const float* __restrict__ d1S, const float* __restrict__ d0S,
    unsigned short* __restrict__ outS,
    const unsigned short* __restrict__ agg1E, const unsigned short* __restrict__ agg0E,
    const unsigned short* __restrict__ yE,
    const float* __restrict__ d1E, const float* __restrict__ d0E,
    unsigned short* __restrict__ outE,
    const unsigned short* __restrict__ W1, const unsigned short* __restrict__ W0,
    const float* __restrict__ b1, const float* __restrict__ b0, int nblkS) {
    constexpr int PITCH = 136;
    __shared__ unsigned short Wl[2 * 128 * PITCH];
    const int t = threadIdx.x;
    for (int idx = t * 8; idx < 128 * 128; idx += 2048) {
        int r = idx >> 7, k = idx & 127;
        *(uint4*)(&Wl[r * PITCH + k]) = *(const uint4*)(&W1[idx]);
        *(uint4*)(&Wl[128 * PITCH + r * PITCH + k]) = *(const uint4*)(&W0[idx]);
    }
    __syncthreads();
    const bool sideE = (int)blockIdx.x >= nblkS;
    const unsigned short* agg1 = sideE ? agg1E : agg1S;
    const unsigned short* agg0 = sideE ? agg0E : agg0S;
    const unsigned short* y    = sideE ? yE : yS;
    const float* d1 = sideE ? d1E : d1S;
    const float* d0 = sideE ? d0E : d0S;
    unsigned short* out = sideE ? outE : outS;
    const int M = sideE ? EN : SN;
    const int lane = t & 63;
    const int nm = lane & 15;
    const int quad = lane >> 4;
    const int row0 = ((int)blockIdx.x - (sideE ? nblkS : 0)) * 64 + (t >> 6) * 16;
    if (row0 >= M) return;

    const float d1v = d1[row0 + nm];
    const float d0v = d0[row0 + nm];

    f32x4 acc[8];
#pragma unroll
    for (int nt = 0; nt < 8; ++nt) acc[nt] = (f32x4){0.f, 0.f, 0.f, 0.f};

    const size_t rbase = (size_t)(row0 + nm) * 128 + quad * 8;
#pragma unroll
    for (int ks = 0; ks < 4; ++ks) {
        uint4 ua1 = *(const uint4*)(agg1 + rbase + ks * 32);
        uint4 ua0 = *(const uint4*)(agg0 + rbase + ks * 32);
        uint4 uy  = *(const uint4*)(y    + rbase + ks * 32);
        uint4 p1, p0;
        {
            unsigned* a1 = (unsigned*)&ua1; unsigned* a0 = (unsigned*)&ua0;
            unsigned* yy = (unsigned*)&uy;
            unsigned* q1 = (unsigned*)&p1; unsigned* q0 = (unsigned*)&p0;
#pragma unroll
            for (int w = 0; w < 4; ++w) {
                float ylo = bf_lo(yy[w]), yhi = bf_hi(yy[w]);
                q1[w] = packbf2(bf_lo(a1[w]) + d1v * ylo, bf_hi(a1[w]) + d1v * yhi);
                q0[w] = packbf2(bf_lo(a0[w]) + d0v * ylo, bf_hi(a0[w]) + d0v * yhi);
            }
        }
        bf16x8 af1 = *(bf16x8*)&p1;
        bf16x8 af0 = *(bf16x8*)&p0;
#pragma unroll
        for (int nt = 0; nt < 8; ++nt) {
            bf16x8 bw1 = *(const bf16x8*)(&Wl[(nt * 16 + nm) * PITCH + ks * 32 + quad * 8]);
            acc[nt] = __builtin_amdgcn_mfma_f32_16x16x32_bf16(af1, bw1, acc[nt], 0, 0, 0);
            bf16x8 bw0 = *(const bf16x8*)(&Wl[128 * PITCH + (nt * 16 + nm) * PITCH + ks * 32 + quad * 8]);
            acc[nt] = __builtin_amdgcn_mfma_f32_16x16x32_bf16(af0, bw0, acc[nt], 0, 0, 0);
        }
    }
    unsigned short* orow = out + (size_t)(row0 + quad * 4) * 128 + nm;
#pragma unroll
    for (int nt = 0; nt < 8; ++nt) {
        float bb = b1[nt * 16 + nm] + b0[nt * 16 + nm];
#pragma unroll
        for (int r = 0; r < 4; ++r)
            orow[(size_t)r * 128 + nt * 16] = packbf1(acc[nt][r] + bb);
    }
}

// ---------------------------------------------------------------------------
// Quad-SPMM: 4 edges per wave instruction. Quarter-wave q handles edge e+q;
// lane c (0..15) covers cols 8c..8c+7 via one uint2 fp8 gather + 4
// cvt_pk_f32_fp8 + 4 packed-f32 FMAs (v_pk_fma_f32). Tag phases separated
// by the sort. Cross-quarter reduce via shfl_xor(16|32); quarter 0 writes
// the pos row, quarter 1 the neg row (16 lanes x 16B coalesced).
// ---------------------------------------------------------------------------
__global__ __launch_bounds__(256) void spmm_all(
    const int* __restrict__ rp, const long long* __restrict__ cv,
    const unsigned char* __restrict__ kd8, const unsigned char* __restrict__ st8,
    unsigned short* __restrict__ as1, unsigned short* __restrict__ as0,
    unsigned short* __restrict__ ae1, unsigned short* __restrict__ ae0) {
    const int wave = (blockIdx.x * 256 + threadIdx.x) >> 6;
    const int lane = threadIdx.x & 63;
    if (wave >= SN + EN) return;
    const bool sideE = wave >= SN;
    const int r = sideE ? wave - SN : wave;
    const int nch = sideE ? NCH1 : NCH0;
    const int* rpb = rp + (sideE ? SIDE1_BASE2 : 0);
    const int q = lane >> 4;           // quarter 0..3 -> edge e+q
    const int c = lane & 15;           // col group: cols 8c..8c+7
    const unsigned char* g8 = (sideE ? st8 : kd8) + c * 8;

    const int rbase = 2 * r * nch;
    const int e0 = rpb[rbase];
    const int em = rpb[rbase + nch];
    const int ee = rpb[rbase + 2 * nch];

    f32x2 accP[4], accN[4];
#pragma unroll
    for (int j = 0; j < 4; ++j) { accP[j] = (f32x2){0.f, 0.f}; accN[j] = (f32x2){0.f, 0.f}; }

#define QUAD(E, ACC)                                                        \
    {                                                                       \
        int col = (int)((E) & 0xFFFF);                                      \
        float v = __int_as_float((int)((E) >> 32));                         \
        f32x2 vv = {v, v};                                                  \
        uint2 u = *(const uint2*)(g8 + (col << 7));                         \
        ACC[0] += vv * __builtin_amdgcn_cvt_pk_f32_fp8((int)u.x, false);    \
        ACC[1] += vv * __builtin_amdgcn_cvt_pk_f32_fp8((int)u.x, true);     \
        ACC[2] += vv * __builtin_amdgcn_cvt_pk_f32_fp8((int)u.y, false);    \
        ACC[3] += vv * __builtin_amdgcn_cvt_pk_f32_fp8((int)u.y, true);     \
    }

    // phase 1: pos edges [e0, em)
    {
        int e = e0;
        for (; e + 16 <= em; e += 16) {
            long long E0 = cv[e + q];
            long long E1 = cv[e + 4 + q];
            long long E2 = cv[e + 8 + q];
            long long E3 = cv[e + 12 + q];
            QUAD(E0, accP) QUAD(E1, accP) QUAD(E2, accP) QUAD(E3, accP)
        }
        for (; e + 4 <= em; e += 4) {
            long long E0 = cv[e + q];
            QUAD(E0, accP)
        }
        if (e < em) {
            int idx = min(e + q, em - 1);
            long long E0 = cv[idx];
            if (e + q >= em) E0 &= 0xFFFFLL;   // keep col, zero value
            QUAD(E0, accP)
        }
    }
    // phase 2: neg edges [em, ee)
    {
        int e = em;
        for (; e + 16 <= ee; e += 16) {
            long long E0 = cv[e + q];
            long long E1 = cv[e + 4 + q];
            long long E2 = cv[e + 8 + q];
            long long E3 = cv[e + 12 + q];
            QUAD(E0, accN) QUAD(E1, accN) QUAD(E2, accN) QUAD(E3, accN)
        }
        for (; e + 4 <= ee; e += 4) {
            long long E0 = cv[e + q];
            QUAD(E0, accN)
        }
        if (e < ee) {
            int idx = min(e + q, ee - 1);
            long long E0 = cv[idx];
            if (e + q >= ee) E0 &= 0xFFFFLL;
            QUAD(E0, accN)
        }
    }
#undef QUAD

    // reduce over quarters (xor 16, then 32)
#pragma unroll
    for (int j = 0; j < 4; ++j) {
        accP[j].x += __shfl_xor(accP[j].x, 16);
        accP[j].y += __shfl_xor(accP[j].y, 16);
        accN[j].x += __shfl_xor(accN[j].x, 16);
        accN[j].y += __shfl_xor(accN[j].y, 16);
        accP[j].x += __shfl_xor(accP[j].x, 32);
        accP[j].y += __shfl_xor(accP[j].y, 32);
        accN[j].x += __shfl_xor(accN[j].x, 32);
        accN[j].y += __shfl_xor(accN[j].y, 32);
    }
    unsigned short* o1 = sideE ? ae1 : as1;
    unsigned short* o0 = sideE ? ae0 : as0;
    const int base = (r << 7) + c * 8;
    if (q == 0) {
        uint4 w;
        w.x = packbf2(accP[0].x, accP[0].y);
        w.y = packbf2(accP[1].x, accP[1].y);
        w.z = packbf2(accP[2].x, accP[2].y);
        w.w = packbf2(accP[3].x, accP[3].y);
        *(uint4*)&o1[base] = w;
    } else if (q == 1) {
        uint4 w;
        w.x = packbf2(accN[0].x, accN[0].y);
        w.y = packbf2(accN[1].x, accN[1].y);
        w.z = packbf2(accN[2].x, accN[2].y);
        w.w = packbf2(accN[3].x, accN[3].y);
        *(uint4*)&o0[base] = w;
    }
}

// ---------------------------------------------------------------------------
// fp32 tiled GEMM for the head: out = act( X @ |W|^T + b )
// ---------------------------------------------------------------------------
template <int KK, int NCOLS, int ROWS, bool ABSW, bool SIG>
__global__ __launch_bounds__(256) void gemm_xwT(const float* __restrict__ X,
                                                const float* __restrict__ W,
                                                const float* __restrict__ bias,
                                                float* __restrict__ out, int M) {
    constexpr int KP = 32;
    constexpr int NG = 256 / NCOLS;
    constexpr int RT = ROWS / NG;
    __shared__ float BT[KP * (NCOLS + 1)];
    __shared__ float Xl[ROWS * (KK + 1)];
    const int t = threadIdx.x;
    const int j = t % NCOLS;
    const int rg = t / NCOLS;
    const int row0 = blockIdx.x * ROWS;

    for (int idx = t; idx < ROWS * KK; idx += 256) {
        int r = idx / KK, k = idx % KK;
        int gr = row0 + r;
        Xl[r * (KK + 1) + k] = (gr < M) ? X[gr * KK + k] : 0.f;
    }
    float acc[RT];
#pragma unroll
    for (int i = 0; i < RT; ++i) acc[i] = 0.f;

    for (int k0 = 0; k0 < KK; k0 += KP) {
        __syncthreads();
        for (int idx = t; idx < NCOLS * KP; idx += 256) {
            int jj = idx / KP, kp = idx % KP;
            float w = W[jj * KK + k0 + kp];
            BT[kp * (NCOLS + 1) + jj] = ABSW ? fabsf(w) : w;
        }
        __syncthreads();
#pragma unroll
        for (int kp = 0; kp < KP; ++kp) {
            float b = BT[kp * (NCOLS + 1) + j];
#pragma unroll
            for (int rr = 0; rr < RT; ++rr)
                acc[rr] += Xl[(rg * RT + rr) * (KK + 1) + k0 + kp] * b;
        }
    }
    float bj = bias ? bias[j] : 0.f;
#pragma unroll
    for (int rr = 0; rr < RT; ++rr) {
        int gr = row0 + rg * RT + rr;
        if (gr < M) {
            float v = acc[rr] + bj;
            out[gr * NCOLS + j] = SIG ? sigmoidf_(v) : v;
        }
    }
}

// ---------------------------------------------------------------------------
// Head kernels
// ---------------------------------------------------------------------------
__global__ __launch_bounds__(128) void head1_kernel(
    const int* __restrict__ stu_id, const int* __restrict__ exer_id,
    const float* __restrict__ kn_emb, const unsigned short* __restrict__ stat,
    const unsigned short* __restrict__ kdiff, const float* __restrict__ stu_bias,
    const float* __restrict__ e_disc, float* __restrict__ x) {
    const int b = blockIdx.x;
    const int k = threadIdx.x;
    const int sid = stu_id[b], eid = exer_id[b];
    float disc = sigmoidf_(e_disc[eid]);
    float sb = sigmoidf_(bf_one(stat[(sid << 7) + k]) + stu_bias[sid]);
    float kd = sigmoidf_(bf_one(kdiff[(eid << 7) + k]));
    x[(b << 7) + k] = disc * (sb - kd) * kn_emb[(b << 7) + k];
}

__global__ __launch_bounds__(256) void pn3_kernel(const float* __restrict__ h2,
                                                  const float* __restrict__ w3,
                                                  const float* __restrict__ b3,
                                                  float* __restrict__ out) {
    __shared__ float wl[128];
    const int t = threadIdx.x;
    if (t < 128) wl[t] = fabsf(w3[t]);
    __syncthreads();
    const int b = blockIdx.x * 256 + t;
    float acc = 0.f;
#pragma unroll 4
    for (int k = 0; k < 128; ++k) acc += h2[(b << 7) + k] * wl[k];
    out[b] = sigmoidf_(acc + b3[0]);
}

// ---------------------------------------------------------------------------
// Launch
// ---------------------------------------------------------------------------
static inline size_t align256(size_t x) { return (x + 255) & ~size_t(255); }

extern "C" void kernel_launch(void* const* d_in, const int* in_sizes, int n_in,
                              void* d_out, int out_size, void* d_ws, size_t ws_size,
                              hipStream_t stream) {
    const int*   stu_id   = (const int*)d_in[0];
    const int*   exer_id  = (const int*)d_in[1];
    const float* kn_emb   = (const float*)d_in[2];
    const float* stu_emb  = (const float*)d_in[3];
    const float* exer_emb = (const float*)d_in[4];
    const float* kn_base  = (const float*)d_in[5];
    const float* stu_bias = (const float*)d_in[6];
    const float* e_disc   = (const float*)d_in[7];
    const float* W1_w     = (const float*)d_in[8];
    const float* W1_b     = (const float*)d_in[9];
    const float* W0_w     = (const float*)d_in[10];
    const float* W0_b     = (const float*)d_in[11];
    const float* pn1_w    = (const float*)d_in[12];
    const float* pn1_b    = (const float*)d_in[13];
    const float* pn2_w    = (const float*)d_in[14];
    const float* pn2_b    = (const float*)d_in[15];
    const float* pn3_w    = (const float*)d_in[16];
    const float* pn3_b    = (const float*)d_in[17];
    const int*   ui1_r = (const int*)d_in[18]; const int* ui1_c = (const int*)d_in[19];
    const float* ui1_v = (const float*)d_in[20];
    const int*   iu1_r = (const int*)d_in[21]; const int* iu1_c = (const int*)d_in[22];
    const float* iu1_v = (const float*)d_in[23];
    const int*   ui0_r = (const int*)d_in[24]; const int* ui0_c = (const int*)d_in[25];
    const float* ui0_v = (const float*)d_in[26];
    const int*   iu0_r = (const int*)d_in[27]; const int* iu0_c = (const int*)d_in[28];
    const float* iu0_v = (const float*)d_in[29];
    const float* d_i_1 = (const float*)d_in[30];
    const float* d_j_1 = (const float*)d_in[31];
    const float* d_i_0 = (const float*)d_in[32];
    const float* d_j_0 = (const float*)d_in[33];
    float* out = (float*)d_out;

    typedef unsigned short u16;
    typedef unsigned char u8;
    char* p = (char*)d_ws;
    size_t off = 0;
    auto alloc = [&](size_t bytes) { char* q = p + off; off += align256(bytes); return q; };
    // bf16 state — stat & kdiff contiguous (bf2fp8 spans both)
    u16* stat  = (u16*)alloc(size_t(SN) * KN * 2);
    u16* kdiff = (u16*)alloc(size_t(EN) * KN * 2);
    // fp8 shadows — contiguous pair
    u8* st8 = (u8*)alloc(size_t(SN) * KN);
    u8* kd8 = (u8*)alloc(size_t(EN) * KN);
    // aggregation buffers
    u16* as1 = (u16*)alloc(size_t(SN) * KN * 2);
    u16* as0 = (u16*)alloc(size_t(SN) * KN * 2);
    u16* ae1 = (u16*)alloc(size_t(EN) * KN * 2);
    u16* ae0 = (u16*)alloc(size_t(EN) * KN * 2);
    // bf16 weight tables
    u16* Kb  = (u16*)alloc(size_t(KN) * DN * 2);
    u16* Wb1 = (u16*)alloc(size_t(KN) * KN * 2);
    u16* Wb0 = (u16*)alloc(size_t(KN) * KN * 2);
    // sort structures
    int*  coarseCnt  = (int*)alloc(512 * 4);
    int*  coarseBase = (int*)alloc((NBIN2 + 1) * 4);
    int*  tails      = (int*)alloc(512 * 4);
    int*  rp_all     = (int*)alloc(size_t(NTOT2 + 1) * 4);
    int2* stg        = (int2*)alloc(size_t(4) * NE * 8);
    int2* cv_all     = (int2*)alloc(size_t(4) * NE * 8);
    // head
    float* xh = (float*)alloc(size_t(BN) * KN * 4);
    float* h1 = (float*)alloc(size_t(BN) * 256 * 4);
    float* h2 = (float*)alloc(size_t(BN) * 128 * 4);
    if (off > ws_size) return;

    CsrB c;
    c.rows[0] = ui1_r; c.cols[0] = ui1_c; c.vals[0] = ui1_v;
    c.rows[1] = ui0_r; c.cols[1] = ui0_c; c.vals[1] = ui0_v;
    c.rows[2] = iu1_r; c.cols[2] = iu1_c; c.vals[2] = iu1_v;
    c.rows[3] = iu0_r; c.cols[3] = iu0_c; c.vals[3] = iu0_v;

    // ---- two-pass partition sort (key = row, tag, chunk) ----
    hipMemsetAsync(coarseCnt, 0, 512 * 4, stream);
    hist_coarse<<<4 * HB, 256, 0, stream>>>(c, coarseCnt);
    scan_coarse<<<1, 512, 0, stream>>>(coarseCnt, coarseBase, tails);
    part1<<<4 * PG1, 512, 0, stream>>>(c, tails, stg);
    part2<<<NBIN2, 512, 0, stream>>>(coarseBase, stg, rp_all, cv_all);

    // ---- bf16 weight conversions ----
    f2bf<<<(KN * DN / 2 + 255) / 256, 256, 0, stream>>>(kn_base, Kb, KN * DN / 2);
    f2bf<<<(KN * KN / 2 + 255) / 256, 256, 0, stream>>>(W1_w, Wb1, KN * KN / 2);
    f2bf<<<(KN * KN / 2 + 255) / 256, 256, 0, stream>>>(W0_w, Wb0, KN * KN / 2);

    // ---- projections (read f32 embeddings directly) ----
    gemm_proj<DN><<<(SN + 63) / 64, 256, 0, stream>>>(stu_emb, Kb, stat, SN);
    gemm_proj<DN><<<(EN + 63) / 64, 256, 0, stream>>>(exer_emb, Kb, kdiff, EN);

    const int N4 = (SN + EN) * KN / 4;   // fp8-shadow conversion span (both tables)
    const int nblkS = (SN + 63) / 64, nblkE = (EN + 63) / 64;

    // ---- GCN layers ----
    for (int l = 0; l < NLAYER; ++l) {
        bf2fp8<<<(N4 + 255) / 256, 256, 0, stream>>>((const unsigned*)stat,
                                                     (unsigned*)st8, N4);
        spmm_all<<<(SN + EN + 3) / 4, 256, 0, stream>>>(
            rp_all, (const long long*)cv_all, kd8, st8, as1, as0, ae1, ae0);
        gemm2_mfma<<<nblkS + nblkE, 256, 0, stream>>>(
            as1, as0, stat, d_i_1, d_i_0, stat,
            ae1, ae0, kdiff, d_j_1, d_j_0, kdiff,
            Wb1, Wb0, W1_b, W0_b, nblkS);
    }

    // ---- head ----
    head1_kernel<<<BN, 128, 0, stream>>>(stu_id, exer_id, kn_emb, stat, kdiff,
                                         stu_bias, e_disc, xh);
    gemm_xwT<128, 256, 16, true, true><<<BN / 16, 256, 0, stream>>>(xh, pn1_w, pn1_b, h1, BN);
    gemm_xwT<256, 128, 32, true, true><<<BN / 32, 256, 0, stream>>>(h1, pn2_w, pn2_b, h2, BN);
    pn3_kernel<<<BN / 256, 256, 0, stream>>>(h2, pn3_w, pn3_b, out);
    (void)out_size; (void)n_in; (void)in_sizes;
}